// Round 8
// baseline (620.783 us; speedup 1.0000x reference)
//
#include <hip/hip_runtime.h>
#include <hip/hip_bf16.h>
#include <math.h>

typedef __bf16 bf16;
typedef __bf16 bf16x8 __attribute__((ext_vector_type(8)));
typedef float  f32x4  __attribute__((ext_vector_type(4)));

#define NB 32768   // batch
#define NU 256     // units (= D)

#define MFMA(a,b,c) __builtin_amdgcn_mfma_f32_16x16x32_bf16((a),(b),(c),0,0,0)

// fast activations: v_rcp + v_exp based (absmax headroom is ~2^-5, these are ~1ulp)
static __device__ __forceinline__ float sigf(float x) {
    return __builtin_amdgcn_rcpf(1.0f + __expf(-x));
}
static __device__ __forceinline__ float tanh_(float x) {
    return fmaf(2.0f, sigf(2.0f * x), -1.0f);   // tanh = 2*sigmoid(2x) - 1
}

// async global->LDS, 16 B per lane. LDS dest must be thread-contiguous
// (base + tid*16); global src is per-lane arbitrary (16B-aligned).
static __device__ __forceinline__ void ld16(bf16* l, const bf16* g) {
    __builtin_amdgcn_global_load_lds(
        (const __attribute__((address_space(1))) void*)g,
        (__attribute__((address_space(3))) void*)l, 16, 0, 0);
}

// Swizzled LDS tile [rows][64] bf16 (128 B/row, 8x 16B chunks).
// Global chunk kc is stored at LDS slot kc^(row&7) (staged via pre-swizzled
// global source address; LDS dest stays linear). 16 lanes reading the same kc
// across consecutive rows then hit 8 distinct 4-bank columns -> conflict-free.
static __device__ __forceinline__ bf16x8 frag64(const bf16* buf, int row, int kc) {
    return *reinterpret_cast<const bf16x8*>(buf + row * 64 + ((kc ^ (row & 7)) * 8));
}

// ---------------------------------------------------------------------------
// fp32 -> bf16 activation conversion. job 0: x -> xs[:,0:256] (stride 512)
// job 1: h_v -> hv_cat[:,0:256] (stride 512); job 2: h_c -> buf256 (stride 256)
// ---------------------------------------------------------------------------
__global__ void k_cvt(const float* __restrict__ x, const float* __restrict__ h_v,
                      const float* __restrict__ h_c,
                      bf16* __restrict__ xs, bf16* __restrict__ hv_cat,
                      bf16* __restrict__ hcb)
{
    const int j = blockIdx.y;
    const int gid = blockIdx.x * 256 + threadIdx.x;   // 8-element index
    const int row = gid >> 5, col = (gid & 31) * 8;
    const float* src = (j == 0) ? x : (j == 1) ? h_v : h_c;
    bf16* dst; int stride;
    if (j == 0)      { dst = xs;     stride = 512; }
    else if (j == 1) { dst = hv_cat; stride = 512; }
    else             { dst = hcb;    stride = 256; }
    const f32x4* s4 = reinterpret_cast<const f32x4*>(src + row * 256 + col);
    const f32x4 a = s4[0], b = s4[1];
    bf16x8 o;
    o[0] = (bf16)a[0]; o[1] = (bf16)a[1]; o[2] = (bf16)a[2]; o[3] = (bf16)a[3];
    o[4] = (bf16)b[0]; o[5] = (bf16)b[1]; o[6] = (bf16)b[2]; o[7] = (bf16)b[3];
    *reinterpret_cast<bf16x8*>(dst + row * stride + col) = o;
}

// ---------------------------------------------------------------------------
// pack g_prev>0 into a bitmask: 33.5 MB int32 -> 1 MB (read by schat + gates)
// ---------------------------------------------------------------------------
__global__ void k_pack(const int* __restrict__ g, unsigned long long* __restrict__ m)
{
    const int tid0 = blockIdx.x * 256 + threadIdx.x;
#pragma unroll
    for (int it = 0; it < 32; ++it) {
        const int i = tid0 + it * (1024 * 256);
        const unsigned long long b = __ballot(g[i] > 0);
        if ((threadIdx.x & 63) == 0) m[i >> 6] = b;
    }
}

// ---------------------------------------------------------------------------
// Tiled transpose: dst[c*dstr + r] = (bf16)src[r*C + c]  (fp32 src)
// 24 jobs; 32x32 tiles; block (32,8)
// ---------------------------------------------------------------------------
struct TrJobs {
    const float* src[24];
    bf16*        dst[24];
    int R[24], C[24], dstr[24];
};

__global__ void k_tr(TrJobs J) {
    __shared__ float tile[32][33];
    const int j = blockIdx.y;
    const int R = J.R[j], C = J.C[j], dstr = J.dstr[j];
    const int tilesC = C >> 5;
    const int tr = blockIdx.x / tilesC, tc = blockIdx.x % tilesC;
    if (tr >= (R >> 5)) return;
    const int r0 = tr * 32, c0 = tc * 32;
    const int tx = threadIdx.x, ty = threadIdx.y;
    const float* src = J.src[j];
    bf16* dst = J.dst[j];
#pragma unroll
    for (int i = 0; i < 4; ++i)
        tile[ty + 8 * i][tx] = src[(r0 + ty + 8 * i) * C + c0 + tx];
    __syncthreads();
#pragma unroll
    for (int i = 0; i < 4; ++i)
        dst[(c0 + ty + 8 * i) * dstr + r0 + tx] = (bf16)tile[tx][ty + 8 * i];
}

// ---------------------------------------------------------------------------
// s_c_hat = where(g_prev>0, h_v@Wv, h_c@Wc) -> xs[:,256:512] (bf16)
// dual GEMM; block tile 128x64; 4 waves each 64x32; K=256, BK=64, swizzled LDS
// ---------------------------------------------------------------------------
__global__ __launch_bounds__(256) void k_schat_t(
    const bf16* __restrict__ hc, const bf16* __restrict__ hvcat,
    const bf16* __restrict__ WTc, const bf16* __restrict__ WTv,
    const unsigned* __restrict__ gmask, bf16* __restrict__ xs)
{
    __shared__ bf16 A1[128 * 64], A2[128 * 64], B1[64 * 64], B2[64 * 64];
    const int tid = threadIdx.x, lane = tid & 63, w = tid >> 6;
    const int lr = lane & 15, hi = lane >> 4;
    const int r0 = blockIdx.x * 128, c0 = blockIdx.y * 64;
    const int wr = w >> 1, wc = w & 1;
    f32x4 acc1[4][2] = {}, acc2[4][2] = {};
    for (int kk = 0; kk < 4; ++kk) {
        const int k0 = kk * 64;
        if (kk) __syncthreads();
#pragma unroll
        for (int p = 0; p < 4; ++p) {
            const int t = tid + p * 256;
            const int row = t >> 3, gs = ((t & 7) ^ (row & 7)) * 8;
            ld16(A1 + t * 8, hc    + (r0 + row) * 256 + k0 + gs);
            ld16(A2 + t * 8, hvcat + (r0 + row) * 512 + k0 + gs);
        }
#pragma unroll
        for (int p = 0; p < 2; ++p) {
            const int t = tid + p * 256;
            const int row = t >> 3, gs = ((t & 7) ^ (row & 7)) * 8;
            ld16(B1 + t * 8, WTc + (c0 + row) * 256 + k0 + gs);
            ld16(B2 + t * 8, WTv + (c0 + row) * 256 + k0 + gs);
        }
        __syncthreads();
#pragma unroll
        for (int ks = 0; ks < 2; ++ks) {
            bf16x8 a1[4], a2[4], b1[2], b2[2];
#pragma unroll
            for (int i = 0; i < 4; ++i) {
                a1[i] = frag64(A1, wr * 64 + i * 16 + lr, ks * 4 + hi);
                a2[i] = frag64(A2, wr * 64 + i * 16 + lr, ks * 4 + hi);
            }
#pragma unroll
            for (int jj = 0; jj < 2; ++jj) {
                b1[jj] = frag64(B1, wc * 32 + jj * 16 + lr, ks * 4 + hi);
                b2[jj] = frag64(B2, wc * 32 + jj * 16 + lr, ks * 4 + hi);
            }
#pragma unroll
            for (int i = 0; i < 4; ++i)
#pragma unroll
                for (int jj = 0; jj < 2; ++jj) {
                    acc1[i][jj] = MFMA(a1[i], b1[jj], acc1[i][jj]);
                    acc2[i][jj] = MFMA(a2[i], b2[jj], acc2[i][jj]);
                }
        }
    }
#pragma unroll
    for (int i = 0; i < 4; ++i)
#pragma unroll
        for (int jj = 0; jj < 2; ++jj)
#pragma unroll
            for (int r = 0; r < 4; ++r) {
                const int row = r0 + wr * 64 + i * 16 + hi * 4 + r;
                const int col = c0 + wc * 32 + jj * 16 + lr;
                const bool gp = (gmask[row * 8 + (col >> 5)] >> (col & 31)) & 1;
                xs[row * 512 + 256 + col] = (bf16)(gp ? acc2[i][jj][r] : acc1[i][jj][r]);
            }
}

// ---------------------------------------------------------------------------
// s_v_hat = hv_cat @ Wsv -> xs[:,256:512]; K=512, tile 128x128, BK=64 swizzled
// ---------------------------------------------------------------------------
__global__ __launch_bounds__(256) void k_svhat_t(
    const bf16* __restrict__ hvcat, const bf16* __restrict__ Wsv,
    bf16* __restrict__ xs)
{
    __shared__ bf16 A[128 * 64], B[128 * 64];
    const int tid = threadIdx.x, lane = tid & 63, w = tid >> 6;
    const int lr = lane & 15, hi = lane >> 4;
    const int r0 = blockIdx.x * 128, c0 = blockIdx.y * 128;
    const int wr = w >> 1, wc = w & 1;
    f32x4 acc[4][4] = {};
    for (int kk = 0; kk < 8; ++kk) {
        const int k0 = kk * 64;
        if (kk) __syncthreads();
#pragma unroll
        for (int p = 0; p < 4; ++p) {
            const int t = tid + p * 256;
            const int row = t >> 3, gs = ((t & 7) ^ (row & 7)) * 8;
            ld16(A + t * 8, hvcat + (r0 + row) * 512 + k0 + gs);
            ld16(B + t * 8, Wsv   + (c0 + row) * 512 + k0 + gs);
        }
        __syncthreads();
#pragma unroll
        for (int ks = 0; ks < 2; ++ks) {
            bf16x8 a[4], b[4];
#pragma unroll
            for (int i = 0; i < 4; ++i) a[i] = frag64(A, wr * 64 + i * 16 + lr, ks * 4 + hi);
#pragma unroll
            for (int jj = 0; jj < 4; ++jj) b[jj] = frag64(B, wc * 64 + jj * 16 + lr, ks * 4 + hi);
#pragma unroll
            for (int i = 0; i < 4; ++i)
#pragma unroll
                for (int jj = 0; jj < 4; ++jj)
                    acc[i][jj] = MFMA(a[i], b[jj], acc[i][jj]);
        }
    }
#pragma unroll
    for (int i = 0; i < 4; ++i)
#pragma unroll
        for (int jj = 0; jj < 4; ++jj)
#pragma unroll
            for (int r = 0; r < 4; ++r) {
                const int row = r0 + wr * 64 + i * 16 + hi * 4 + r;
                const int col = c0 + wc * 64 + jj * 16 + lr;
                xs[row * 512 + 256 + col] = (bf16)acc[i][jj][r];
            }
}

// ---------------------------------------------------------------------------
// Gates GEMM + cell update, BARRIER-FREE main loop.
// Block = 512 threads (8 waves), tile 256 rows x 128 cols (4 gates x 32 u).
// B tile (128 rows x K=512 = 128 KB) staged into LDS ONCE (chunk-swizzled),
// single __syncthreads; then 16 k-slices with A read per-wave directly from
// L2-resident xs into registers and B broadcast from LDS. No per-step barrier
// -> compiler free to prefetch a-loads arbitrarily deep.
// mode 0 = click branch, mode 1 = conversion branch.
// ---------------------------------------------------------------------------
__global__ __launch_bounds__(512, 2) void k_gates_t(
    const bf16* __restrict__ xs, const bf16* __restrict__ WgT,
    const float* __restrict__ bx, const float* __restrict__ click,
    const unsigned* __restrict__ gmask, const float* __restrict__ s_prev,
    const float* __restrict__ h_prev,
    float* __restrict__ out_s, float* __restrict__ out_h,
    float* __restrict__ out_g, bf16* __restrict__ hnb,
    bf16* __restrict__ hmask_dst, int mode)
{
    __shared__ bf16 Bs[128 * 512];            // 128 KB, per-row chunk-swizzled
    const int tid = threadIdx.x, lane = tid & 63, w = tid >> 6;   // w: 0..7
    const int lr = lane & 15, hi = lane >> 4;
    const int r0 = blockIdx.x * 256, u0 = blockIdx.y * 32;

    // stage whole B tile once: 8192 chunks of 16 B; 512 threads x 16 passes.
    // dest chunk t = (row, c); source chunk sc = c ^ (row&7)  (involution)
#pragma unroll
    for (int p = 0; p < 16; ++p) {
        const int t = tid + p * 512;
        const int row = t >> 6, c = t & 63;
        const int sc = c ^ (row & 7);
        const int g = row >> 5, ul = row & 31;
        ld16(Bs + t * 8, WgT + (g * 256 + u0 + ul) * 512 + sc * 8);
    }
    __syncthreads();   // the ONLY barrier (drains the global_load_lds queue)

    // per-wave A base: rows w*32 + i*16 + lr of this block's 256-row stripe
    const bf16* ap = xs + (size_t)(r0 + w * 32 + lr) * 512 + hi * 8;

    f32x4 acc[2][8] = {};
#pragma unroll
    for (int ksl = 0; ksl < 16; ++ksl) {      // 32-col k-slices
        bf16x8 a[2], b[8];
#pragma unroll
        for (int i = 0; i < 2; ++i)
            a[i] = *reinterpret_cast<const bf16x8*>(ap + i * 16 * 512 + ksl * 32);
#pragma unroll
        for (int nb = 0; nb < 8; ++nb) {
            const int row = nb * 16 + lr;
            const int c = ksl * 4 + hi;       // global chunk within row (0..63)
            b[nb] = *reinterpret_cast<const bf16x8*>(
                Bs + row * 512 + ((c ^ (row & 7)) * 8));
        }
#pragma unroll
        for (int i = 0; i < 2; ++i)
#pragma unroll
            for (int nb = 0; nb < 8; ++nb)
                acc[i][nb] = MFMA(a[i], b[nb], acc[i][nb]);
    }

    // epilogue: gate gg lives in acc[i][gg*2 + uh]
    const int u0b = u0 >> 5;
    float bfv[2], biv[2], bov[2], bgv[2];
#pragma unroll
    for (int uh = 0; uh < 2; ++uh) {
        const int u = u0 + uh * 16 + lr;
        bfv[uh] = bx[u];       biv[uh] = bx[256 + u];
        bov[uh] = bx[512 + u]; bgv[uh] = bx[768 + u];
    }
#pragma unroll
    for (int i = 0; i < 2; ++i)
#pragma unroll
        for (int r = 0; r < 4; ++r) {
            const int row = r0 + w * 32 + i * 16 + hi * 4 + r;
            const float ck = click[row];
            const unsigned mw = (mode == 0) ? gmask[row * 8 + u0b] : 0u;
#pragma unroll
            for (int uh = 0; uh < 2; ++uh) {
                const int u = u0 + uh * 16 + lr;
                const int o = row * 256 + u;
                const float f  = sigf(acc[i][0 + uh][r] + bfv[uh]);
                const float ii = sigf(acc[i][2 + uh][r] + biv[uh]);
                const float oo = sigf(acc[i][4 + uh][r] + bov[uh]);
                const float gg = tanh_(acc[i][6 + uh][r] + bgv[uh]);
                if (mode == 0) {
                    const bool gp = (mw >> (u & 31)) & 1;
                    const float sn = ii * gg + (gp ? 0.0f : f * s_prev[o]);
                    const float hn = oo * tanh_(sn);
                    out_s[o] = sn;
                    out_h[o] = hn;
                    hnb[o]   = (bf16)hn;
                    hmask_dst[row * 512 + 256 + u] =
                        (ck >= 0.5f) ? (bf16)hn : (bf16)0.0f;
                } else {
                    const bool m = ck >= 0.5f;
                    const float sv = s_prev[o];
                    const float sn = m ? (f * sv + ii * gg) : sv;
                    const float hn = m ? (oo * tanh_(sn)) : h_prev[o];
                    out_s[o] = sn;
                    out_h[o] = hn;
                    out_g[o] = m ? 1.0f : 0.0f;
                    hnb[o]   = (bf16)hn;
                }
            }
        }
}

// ---------------------------------------------------------------------------
// Fused MLP: leaky(H@W0+b0) -> leaky(@W1+b1) -> sigmoid(dot(wf)+bf) [*scale]
// One block = 64 rows; 4 waves x 16 rows; layer-1 output kept in LDS (swizzled)
// ---------------------------------------------------------------------------
__global__ __launch_bounds__(256) void k_mlp_f(
    const bf16* __restrict__ Hin,          // [NB][256]
    const bf16* __restrict__ WT0,          // [128][256]
    const float* __restrict__ b0,          // [128]
    const bf16* __restrict__ WT1,          // [64][128]
    const float* __restrict__ b1,          // [64]
    const float* __restrict__ wf,          // [64]
    const float* __restrict__ bf_,         // [1]
    const float* __restrict__ scale,       // null or [NB]
    float* __restrict__ outp)              // [NB]
{
    __shared__ bf16 A[64 * 64], Bb[128 * 64], H1[64 * 128];
    const int tid = threadIdx.x, lane = tid & 63, w = tid >> 6;
    const int lr = lane & 15, hi = lane >> 4;
    const int r0 = blockIdx.x * 64;
    // ---- layer 1: [64x256] @ [256x128] ----
    f32x4 acc[8] = {};
    for (int kk = 0; kk < 4; ++kk) {
        const int k0 = kk * 64;
        if (kk) __syncthreads();
#pragma unroll
        for (int p = 0; p < 2; ++p) {
            const int t = tid + p * 256;
            const int row = t >> 3, gs = ((t & 7) ^ (row & 7)) * 8;
            ld16(A + t * 8, Hin + (r0 + row) * 256 + k0 + gs);
        }
#pragma unroll
        for (int p = 0; p < 4; ++p) {
            const int t = tid + p * 256;
            const int row = t >> 3, gs = ((t & 7) ^ (row & 7)) * 8;
            ld16(Bb + t * 8, WT0 + row * 256 + k0 + gs);
        }
        __syncthreads();
#pragma unroll
        for (int ks = 0; ks < 2; ++ks) {
            const bf16x8 a = frag64(A, w * 16 + lr, ks * 4 + hi);
            bf16x8 b[8];
#pragma unroll
            for (int nb = 0; nb < 8; ++nb) b[nb] = frag64(Bb, nb * 16 + lr, ks * 4 + hi);
#pragma unroll
            for (int nb = 0; nb < 8; ++nb) acc[nb] = MFMA(a, b[nb], acc[nb]);
        }
    }
    // layer-1 epilogue -> H1 [64][128], chunk-swizzled like frag64 expects
#pragma unroll
    for (int nb = 0; nb < 8; ++nb) {
        const int col = nb * 16 + lr;
        const float bb = b0[col];
#pragma unroll
        for (int r = 0; r < 4; ++r) {
            const int rl = w * 16 + hi * 4 + r;
            float v = acc[nb][r] + bb;
            v = v > 0.0f ? v : 0.3f * v;
            H1[rl * 128 + (((col >> 3) ^ (rl & 7)) * 8) + (col & 7)] = (bf16)v;
        }
    }
    __syncthreads();
    // ---- layer 2: [64x128] @ [128x64] ----
    f32x4 acc2[4] = {};
    for (int kk = 0; kk < 2; ++kk) {
#pragma unroll
        for (int p = 0; p < 2; ++p) {
            const int t = tid + p * 256;
            const int row = t >> 3, gs = ((t & 7) ^ (row & 7)) * 8;
            ld16(Bb + t * 8, WT1 + row * 128 + kk * 64 + gs);
        }
        __syncthreads();
#pragma unroll
        for (int ks = 0; ks < 2; ++ks) {
            const int rl = w * 16 + lr;
            const int c = kk * 8 + ks * 4 + hi;           // global 16B chunk of K=128
            const bf16x8 a = *reinterpret_cast<const bf16x8*>(
                H1 + rl * 128 + ((c ^ (rl & 7)) * 8));
            bf16x8 b[4];
#pragma unroll
            for (int jj = 0; jj < 4; ++jj) b[jj] = frag64(Bb, jj * 16 + lr, ks * 4 + hi);
#pragma unroll
            for (int jj = 0; jj < 4; ++jj) acc2[jj] = MFMA(a, b[jj], acc2[jj]);
        }
        __syncthreads();
    }
    // ---- layer 3: per-row dot(64) + sigmoid (+scale), shfl reduce over lr ----
    float b1v[4], wfv[4];
#pragma unroll
    for (int jj = 0; jj < 4; ++jj) {
        b1v[jj] = b1[jj * 16 + lr];
        wfv[jj] = wf[jj * 16 + lr];
    }
    const float bfv = bf_[0];
#pragma unroll
    for (int r = 0; r < 4; ++r) {
        float p = 0.0f;
#pragma unroll
        for (int jj = 0; jj < 4; ++jj) {
            float v = acc2[jj][r] + b1v[jj];
            v = v > 0.0f ? v : 0.3f * v;
            p = fmaf(v, wfv[jj], p);
        }
        p += __shfl_xor(p, 1); p += __shfl_xor(p, 2);
        p += __shfl_xor(p, 4); p += __shfl_xor(p, 8);
        if (lr == 0) {
            const int row = r0 + w * 16 + hi * 4 + r;
            float res = sigf(p + bfv);
            if (scale) res *= scale[row];
            outp[row] = res;
        }
    }
}

// ---------------------------------------------------------------------------
extern "C" void kernel_launch(void* const* d_in, const int* in_sizes, int n_in,
                              void* d_out, int out_size, void* d_ws, size_t ws_size,
                              hipStream_t stream)
{
    const float* x         = (const float*)d_in[0];
    const float* click     = (const float*)d_in[1];
    const float* h_c       = (const float*)d_in[2];
    const float* h_v       = (const float*)d_in[3];
    const float* s_c       = (const float*)d_in[4];
    const float* s_v       = (const float*)d_in[5];
    const int*   g_prev    = (const int*)d_in[6];
    const float* Wx_c      = (const float*)d_in[7];
    const float* bx_c      = (const float*)d_in[8];
    const float* Wh_c      = (const float*)d_in[9];
    const float* Wx_v      = (const float*)d_in[10];
    const float* bx_v      = (const float*)d_in[11];
    const float* Wh_v      = (const float*)d_in[12];
    const float* W_schat_c = (const float*)d_in[13];
    const float* W_schat_v = (const float*)d_in[14];
    const float* W_svhat_v = (const float*)d_in[15];
    const float* W_svhat_c = (const float*)d_in[16];
    const float* Wpc0 = (const float*)d_in[17];
    const float* bpc0 = (const float*)d_in[18];
    const float* Wpc1 = (const float*)d_in[19];
    const float* bpc1 = (const float*)d_in[20];
    const float* Wfcc = (const float*)d_in[21];
    const float* bfcc = (const float*)d_in[22];
    const float* Wpv0 = (const float*)d_in[23];
    const float* bpv0 = (const float*)d_in[24];
    const float* Wpv1 = (const float*)d_in[25];
    const float* bpv1 = (const float*)d_in[26];
    const float* Wfcv = (const float*)d_in[27];
    const float* bfcv = (const float*)d_in[28];

    // output layout (fp32, concatenated in return order)
    float* out     = (float*)d_out;
    float* out_hcp = out;
    float* out_hvp = out + NB;
    float* out_hcn = out + 2 * NB;
    float* out_hvn = out_hcn + NB * NU;
    float* out_scn = out_hvn + NB * NU;
    float* out_svn = out_scn + NB * NU;
    float* out_gnw = out_svn + NB * NU;

    // workspace carve: gmask first (8B aligned), then bf16 buffers
    unsigned long long* gmask64 = (unsigned long long*)d_ws;   // 131072 u64 = 1 MB
    const unsigned* gmask32 = (const unsigned*)d_ws;
    bf16* w = (bf16*)d_ws + 524288;                            // skip 1 MB
    bf16* WTc    = w; w += 256 * 256;        // W_schat_c^T
    bf16* WTv    = w; w += 256 * 256;        // W_schat_v^T
    bf16* Wsv    = w; w += 256 * 512;        // [W_svhat_v ; W_svhat_c]^T concat-K
    bf16* WT_pc0 = w; w += 128 * 256;
    bf16* WT_pv0 = w; w += 128 * 256;
    bf16* WT_pc1 = w; w += 64 * 128;
    bf16* WT_pv1 = w; w += 64 * 128;
    bf16* WgT_c  = w; w += 4 * 256 * 512;
    bf16* WgT_v  = w; w += 4 * 256 * 512;
    bf16* xs     = w; w += NB * 512;         // [x_bf | s_hat] (both branches)
    bf16* hv_cat = w; w += NB * 512;         // [h_v_bf | click-masked h_c_n]
    bf16* buf256 = w; w += NB * 256;         // h_c_bf -> hcnb -> hvnb (aliased)

    // --- weight prep jobs ---
    TrJobs J;
    int j = 0;
    J.src[j] = W_schat_c; J.dst[j] = WTc; J.R[j] = 256; J.C[j] = 256; J.dstr[j] = 256; ++j;
    J.src[j] = W_schat_v; J.dst[j] = WTv; J.R[j] = 256; J.C[j] = 256; J.dstr[j] = 256; ++j;
    J.src[j] = W_svhat_v; J.dst[j] = Wsv;       J.R[j] = 256; J.C[j] = 256; J.dstr[j] = 512; ++j;
    J.src[j] = W_svhat_c; J.dst[j] = Wsv + 256; J.R[j] = 256; J.C[j] = 256; J.dstr[j] = 512; ++j;
    J.src[j] = Wpc0; J.dst[j] = WT_pc0; J.R[j] = 256; J.C[j] = 128; J.dstr[j] = 256; ++j;
    J.src[j] = Wpv0; J.dst[j] = WT_pv0; J.R[j] = 256; J.C[j] = 128; J.dstr[j] = 256; ++j;
    J.src[j] = Wpc1; J.dst[j] = WT_pc1; J.R[j] = 128; J.C[j] = 64;  J.dstr[j] = 128; ++j;
    J.src[j] = Wpv1; J.dst[j] = WT_pv1; J.R[j] = 128; J.C[j] = 64;  J.dstr[j] = 128; ++j;
    for (int g = 0; g < 4; ++g) {
        J.src[j] = Wx_c + g * 65536; J.dst[j] = WgT_c + g * 131072;       J.R[j] = 256; J.C[j] = 256; J.dstr[j] = 512; ++j;
        J.src[j] = Wh_c + g * 65536; J.dst[j] = WgT_c + g * 131072 + 256; J.R[j] = 256; J.C[j] = 256; J.dstr[j] = 512; ++j;
    }
    for (int g = 0; g < 4; ++g) {
        J.src[j] = Wx_v + g * 65536; J.dst[j] = WgT_v + g * 131072;       J.R[j] = 256; J.C[j] = 256; J.dstr[j] = 512; ++j;
        J.src[j] = Wh_v + g * 65536; J.dst[j] = WgT_v + g * 131072 + 256; J.R[j] = 256; J.C[j] = 256; J.dstr[j] = 512; ++j;
    }

    k_cvt<<<dim3(4096, 3), 256, 0, stream>>>(x, h_v, h_c, xs, hv_cat, buf256);
    k_pack<<<1024, 256, 0, stream>>>(g_prev, gmask64);
    k_tr<<<dim3(64, 24), dim3(32, 8), 0, stream>>>(J);

    // click branch
    k_schat_t<<<dim3(256, 4), 256, 0, stream>>>(buf256, hv_cat, WTc, WTv, gmask32, xs);
    k_gates_t<<<dim3(128, 8), 512, 0, stream>>>(xs, WgT_c, bx_c, click, gmask32, s_c,
                                                nullptr, out_scn, out_hcn, nullptr,
                                                buf256, hv_cat, 0);
    k_mlp_f<<<512, 256, 0, stream>>>(buf256, WT_pc0, bpc0, WT_pc1, bpc1,
                                     Wfcc, bfcc, nullptr, out_hcp);

    // conversion branch
    k_svhat_t<<<dim3(256, 2), 256, 0, stream>>>(hv_cat, Wsv, xs);
    k_gates_t<<<dim3(128, 8), 512, 0, stream>>>(xs, WgT_v, bx_v, click, gmask32, s_v,
                                                h_v, out_svn, out_hvn, out_gnw,
                                                buf256, nullptr, 1);
    k_mlp_f<<<512, 256, 0, stream>>>(buf256, WT_pv0, bpv0, WT_pv1, bpv1,
                                     Wfcv, bfcv, out_hcp, out_hvp);
}

// Round 9
// 587.615 us; speedup vs baseline: 1.0564x; 1.0564x over previous
//
#include <hip/hip_runtime.h>
#include <hip/hip_bf16.h>
#include <math.h>

typedef __bf16 bf16;
typedef __bf16 bf16x8 __attribute__((ext_vector_type(8)));
typedef float  f32x4  __attribute__((ext_vector_type(4)));

#define NB 32768   // batch
#define NU 256     // units (= D)

#define MFMA(a,b,c) __builtin_amdgcn_mfma_f32_16x16x32_bf16((a),(b),(c),0,0,0)

// fast activations: v_rcp + v_exp based (absmax headroom is ~2^-5, these are ~1ulp)
static __device__ __forceinline__ float sigf(float x) {
    return __builtin_amdgcn_rcpf(1.0f + __expf(-x));
}
static __device__ __forceinline__ float tanh_(float x) {
    return fmaf(2.0f, sigf(2.0f * x), -1.0f);   // tanh = 2*sigmoid(2x) - 1
}

// async global->LDS, 16 B per lane. LDS dest must be thread-contiguous
// (base + tid*16); global src is per-lane arbitrary (16B-aligned).
static __device__ __forceinline__ void ld16(bf16* l, const bf16* g) {
    __builtin_amdgcn_global_load_lds(
        (const __attribute__((address_space(1))) void*)g,
        (__attribute__((address_space(3))) void*)l, 16, 0, 0);
}

// Swizzled LDS tile [rows][64] bf16 (128 B/row, 8x 16B chunks).
// Global chunk kc is stored at LDS slot kc^(row&7) (staged via pre-swizzled
// global source address; LDS dest stays linear). 16 lanes reading the same kc
// across consecutive rows then hit 8 distinct 4-bank columns -> conflict-free.
static __device__ __forceinline__ bf16x8 frag64(const bf16* buf, int row, int kc) {
    return *reinterpret_cast<const bf16x8*>(buf + row * 64 + ((kc ^ (row & 7)) * 8));
}

// ---------------------------------------------------------------------------
// fp32 -> bf16 activation conversion. job 0: x -> xs[:,0:256] (stride 512)
// job 1: h_v -> hv_cat[:,0:256] (stride 512); job 2: h_c -> buf256 (stride 256)
// ---------------------------------------------------------------------------
__global__ void k_cvt(const float* __restrict__ x, const float* __restrict__ h_v,
                      const float* __restrict__ h_c,
                      bf16* __restrict__ xs, bf16* __restrict__ hv_cat,
                      bf16* __restrict__ hcb)
{
    const int j = blockIdx.y;
    const int gid = blockIdx.x * 256 + threadIdx.x;   // 8-element index
    const int row = gid >> 5, col = (gid & 31) * 8;
    const float* src = (j == 0) ? x : (j == 1) ? h_v : h_c;
    bf16* dst; int stride;
    if (j == 0)      { dst = xs;     stride = 512; }
    else if (j == 1) { dst = hv_cat; stride = 512; }
    else             { dst = hcb;    stride = 256; }
    const f32x4* s4 = reinterpret_cast<const f32x4*>(src + row * 256 + col);
    const f32x4 a = s4[0], b = s4[1];
    bf16x8 o;
    o[0] = (bf16)a[0]; o[1] = (bf16)a[1]; o[2] = (bf16)a[2]; o[3] = (bf16)a[3];
    o[4] = (bf16)b[0]; o[5] = (bf16)b[1]; o[6] = (bf16)b[2]; o[7] = (bf16)b[3];
    *reinterpret_cast<bf16x8*>(dst + row * stride + col) = o;
}

// ---------------------------------------------------------------------------
// pack g_prev>0 into a bitmask: 33.5 MB int32 -> 1 MB (read by schat + gates)
// ---------------------------------------------------------------------------
__global__ void k_pack(const int* __restrict__ g, unsigned long long* __restrict__ m)
{
    const int tid0 = blockIdx.x * 256 + threadIdx.x;
#pragma unroll
    for (int it = 0; it < 32; ++it) {
        const int i = tid0 + it * (1024 * 256);
        const unsigned long long b = __ballot(g[i] > 0);
        if ((threadIdx.x & 63) == 0) m[i >> 6] = b;
    }
}

// ---------------------------------------------------------------------------
// Tiled transpose: dst[c*dstr + r] = (bf16)src[r*C + c]  (fp32 src)
// 24 jobs; 32x32 tiles; block (32,8)
// ---------------------------------------------------------------------------
struct TrJobs {
    const float* src[24];
    bf16*        dst[24];
    int R[24], C[24], dstr[24];
};

__global__ void k_tr(TrJobs J) {
    __shared__ float tile[32][33];
    const int j = blockIdx.y;
    const int R = J.R[j], C = J.C[j], dstr = J.dstr[j];
    const int tilesC = C >> 5;
    const int tr = blockIdx.x / tilesC, tc = blockIdx.x % tilesC;
    if (tr >= (R >> 5)) return;
    const int r0 = tr * 32, c0 = tc * 32;
    const int tx = threadIdx.x, ty = threadIdx.y;
    const float* src = J.src[j];
    bf16* dst = J.dst[j];
#pragma unroll
    for (int i = 0; i < 4; ++i)
        tile[ty + 8 * i][tx] = src[(r0 + ty + 8 * i) * C + c0 + tx];
    __syncthreads();
#pragma unroll
    for (int i = 0; i < 4; ++i)
        dst[(c0 + ty + 8 * i) * dstr + r0 + tx] = (bf16)tile[tx][ty + 8 * i];
}

// ---------------------------------------------------------------------------
// s_c_hat = where(g_prev>0, h_v@Wv, h_c@Wc) -> xs[:,256:512] (bf16)
// dual GEMM; block tile 128x64; 4 waves each 64x32; K=256, BK=64, swizzled LDS
// ---------------------------------------------------------------------------
__global__ __launch_bounds__(256) void k_schat_t(
    const bf16* __restrict__ hc, const bf16* __restrict__ hvcat,
    const bf16* __restrict__ WTc, const bf16* __restrict__ WTv,
    const unsigned* __restrict__ gmask, bf16* __restrict__ xs)
{
    __shared__ bf16 A1[128 * 64], A2[128 * 64], B1[64 * 64], B2[64 * 64];
    const int tid = threadIdx.x, lane = tid & 63, w = tid >> 6;
    const int lr = lane & 15, hi = lane >> 4;
    const int r0 = blockIdx.x * 128, c0 = blockIdx.y * 64;
    const int wr = w >> 1, wc = w & 1;
    f32x4 acc1[4][2] = {}, acc2[4][2] = {};
    for (int kk = 0; kk < 4; ++kk) {
        const int k0 = kk * 64;
        if (kk) __syncthreads();
#pragma unroll
        for (int p = 0; p < 4; ++p) {
            const int t = tid + p * 256;
            const int row = t >> 3, gs = ((t & 7) ^ (row & 7)) * 8;
            ld16(A1 + t * 8, hc    + (r0 + row) * 256 + k0 + gs);
            ld16(A2 + t * 8, hvcat + (r0 + row) * 512 + k0 + gs);
        }
#pragma unroll
        for (int p = 0; p < 2; ++p) {
            const int t = tid + p * 256;
            const int row = t >> 3, gs = ((t & 7) ^ (row & 7)) * 8;
            ld16(B1 + t * 8, WTc + (c0 + row) * 256 + k0 + gs);
            ld16(B2 + t * 8, WTv + (c0 + row) * 256 + k0 + gs);
        }
        __syncthreads();
#pragma unroll
        for (int ks = 0; ks < 2; ++ks) {
            bf16x8 a1[4], a2[4], b1[2], b2[2];
#pragma unroll
            for (int i = 0; i < 4; ++i) {
                a1[i] = frag64(A1, wr * 64 + i * 16 + lr, ks * 4 + hi);
                a2[i] = frag64(A2, wr * 64 + i * 16 + lr, ks * 4 + hi);
            }
#pragma unroll
            for (int jj = 0; jj < 2; ++jj) {
                b1[jj] = frag64(B1, wc * 32 + jj * 16 + lr, ks * 4 + hi);
                b2[jj] = frag64(B2, wc * 32 + jj * 16 + lr, ks * 4 + hi);
            }
#pragma unroll
            for (int i = 0; i < 4; ++i)
#pragma unroll
                for (int jj = 0; jj < 2; ++jj) {
                    acc1[i][jj] = MFMA(a1[i], b1[jj], acc1[i][jj]);
                    acc2[i][jj] = MFMA(a2[i], b2[jj], acc2[i][jj]);
                }
        }
    }
#pragma unroll
    for (int i = 0; i < 4; ++i)
#pragma unroll
        for (int jj = 0; jj < 2; ++jj)
#pragma unroll
            for (int r = 0; r < 4; ++r) {
                const int row = r0 + wr * 64 + i * 16 + hi * 4 + r;
                const int col = c0 + wc * 32 + jj * 16 + lr;
                const bool gp = (gmask[row * 8 + (col >> 5)] >> (col & 31)) & 1;
                xs[row * 512 + 256 + col] = (bf16)(gp ? acc2[i][jj][r] : acc1[i][jj][r]);
            }
}

// ---------------------------------------------------------------------------
// s_v_hat = hv_cat @ Wsv -> xs[:,256:512]; K=512, tile 128x128, BK=64 swizzled
// ---------------------------------------------------------------------------
__global__ __launch_bounds__(256) void k_svhat_t(
    const bf16* __restrict__ hvcat, const bf16* __restrict__ Wsv,
    bf16* __restrict__ xs)
{
    __shared__ bf16 A[128 * 64], B[128 * 64];
    const int tid = threadIdx.x, lane = tid & 63, w = tid >> 6;
    const int lr = lane & 15, hi = lane >> 4;
    const int r0 = blockIdx.x * 128, c0 = blockIdx.y * 128;
    const int wr = w >> 1, wc = w & 1;
    f32x4 acc[4][4] = {};
    for (int kk = 0; kk < 8; ++kk) {
        const int k0 = kk * 64;
        if (kk) __syncthreads();
#pragma unroll
        for (int p = 0; p < 4; ++p) {
            const int t = tid + p * 256;
            const int row = t >> 3, gs = ((t & 7) ^ (row & 7)) * 8;
            ld16(A + t * 8, hvcat + (r0 + row) * 512 + k0 + gs);
            ld16(B + t * 8, Wsv   + (c0 + row) * 512 + k0 + gs);
        }
        __syncthreads();
#pragma unroll
        for (int ks = 0; ks < 2; ++ks) {
            bf16x8 a[4], b[4];
#pragma unroll
            for (int i = 0; i < 4; ++i) a[i] = frag64(A, wr * 64 + i * 16 + lr, ks * 4 + hi);
#pragma unroll
            for (int jj = 0; jj < 4; ++jj) b[jj] = frag64(B, wc * 64 + jj * 16 + lr, ks * 4 + hi);
#pragma unroll
            for (int i = 0; i < 4; ++i)
#pragma unroll
                for (int jj = 0; jj < 4; ++jj)
                    acc[i][jj] = MFMA(a[i], b[jj], acc[i][jj]);
        }
    }
#pragma unroll
    for (int i = 0; i < 4; ++i)
#pragma unroll
        for (int jj = 0; jj < 4; ++jj)
#pragma unroll
            for (int r = 0; r < 4; ++r) {
                const int row = r0 + wr * 64 + i * 16 + hi * 4 + r;
                const int col = c0 + wc * 64 + jj * 16 + lr;
                xs[row * 512 + 256 + col] = (bf16)acc[i][jj][r];
            }
}

// ---------------------------------------------------------------------------
// Gates GEMM + cell update. A = xs (K=512, BK=64); B tile = 4 gates x 32 u.
// REGISTER-DIET tile: block = 64 rows x 128 cols, 4 waves each 16 rows.
// acc[8] = 32 AGPRs (was 64) -> effective regs ~102/thread -> ~5 waves/SIMD
// (~20 waves/CU vs 12). TLP is the proven latency-hiding lever (r4/r5/r8:
// every variant that cut resident waves regressed). Same r2 staging/swizzle.
// mode 0 = click branch, mode 1 = conversion branch.
// ---------------------------------------------------------------------------
__global__ __launch_bounds__(256) void k_gates_t(
    const bf16* __restrict__ xs, const bf16* __restrict__ WgT,
    const float* __restrict__ bx, const float* __restrict__ click,
    const unsigned* __restrict__ gmask, const float* __restrict__ s_prev,
    const float* __restrict__ h_prev,
    float* __restrict__ out_s, float* __restrict__ out_h,
    float* __restrict__ out_g, bf16* __restrict__ hnb,
    bf16* __restrict__ hmask_dst, int mode)
{
    __shared__ bf16 A[64 * 64], B[128 * 64];       // 8 KB + 16 KB
    const int tid = threadIdx.x, lane = tid & 63, w = tid >> 6;
    const int lr = lane & 15, hi = lane >> 4;
    const int r0 = blockIdx.x * 64, u0 = blockIdx.y * 32;
    f32x4 acc[8] = {};
    for (int kk = 0; kk < 8; ++kk) {
        const int k0 = kk * 64;
        if (kk) __syncthreads();
#pragma unroll
        for (int p = 0; p < 2; ++p) {
            const int t = tid + p * 256;
            const int row = t >> 3, gs = ((t & 7) ^ (row & 7)) * 8;
            ld16(A + t * 8, xs + (r0 + row) * 512 + k0 + gs);
        }
#pragma unroll
        for (int p = 0; p < 4; ++p) {
            const int t = tid + p * 256;
            const int row = t >> 3, gs = ((t & 7) ^ (row & 7)) * 8;
            const int g = row >> 5, ul = row & 31;
            ld16(B + t * 8, WgT + (g * 256 + u0 + ul) * 512 + k0 + gs);
        }
        __syncthreads();
#pragma unroll
        for (int ks = 0; ks < 2; ++ks) {
            const bf16x8 a = frag64(A, w * 16 + lr, ks * 4 + hi);
            bf16x8 b[8];
#pragma unroll
            for (int nb = 0; nb < 8; ++nb) b[nb] = frag64(B, nb * 16 + lr, ks * 4 + hi);
#pragma unroll
            for (int nb = 0; nb < 8; ++nb) acc[nb] = MFMA(a, b[nb], acc[nb]);
        }
    }
    // epilogue: gate gg lives in acc[gg*2 + uh]
    const int u0b = u0 >> 5;
    float bfv[2], biv[2], bov[2], bgv[2];
#pragma unroll
    for (int uh = 0; uh < 2; ++uh) {
        const int u = u0 + uh * 16 + lr;
        bfv[uh] = bx[u];       biv[uh] = bx[256 + u];
        bov[uh] = bx[512 + u]; bgv[uh] = bx[768 + u];
    }
#pragma unroll
    for (int r = 0; r < 4; ++r) {
        const int row = r0 + w * 16 + hi * 4 + r;
        const float ck = click[row];
        const unsigned mw = (mode == 0) ? gmask[row * 8 + u0b] : 0u;
#pragma unroll
        for (int uh = 0; uh < 2; ++uh) {
            const int u = u0 + uh * 16 + lr;
            const int o = row * 256 + u;
            const float f  = sigf(acc[0 + uh][r] + bfv[uh]);
            const float ii = sigf(acc[2 + uh][r] + biv[uh]);
            const float oo = sigf(acc[4 + uh][r] + bov[uh]);
            const float gg = tanh_(acc[6 + uh][r] + bgv[uh]);
            if (mode == 0) {
                const bool gp = (mw >> (u & 31)) & 1;
                const float sn = ii * gg + (gp ? 0.0f : f * s_prev[o]);
                const float hn = oo * tanh_(sn);
                out_s[o] = sn;
                out_h[o] = hn;
                hnb[o]   = (bf16)hn;
                hmask_dst[row * 512 + 256 + u] =
                    (ck >= 0.5f) ? (bf16)hn : (bf16)0.0f;
            } else {
                const bool m = ck >= 0.5f;
                const float sv = s_prev[o];
                const float sn = m ? (f * sv + ii * gg) : sv;
                const float hn = m ? (oo * tanh_(sn)) : h_prev[o];
                out_s[o] = sn;
                out_h[o] = hn;
                out_g[o] = m ? 1.0f : 0.0f;
                hnb[o]   = (bf16)hn;
            }
        }
    }
}

// ---------------------------------------------------------------------------
// Fused MLP: leaky(H@W0+b0) -> leaky(@W1+b1) -> sigmoid(dot(wf)+bf) [*scale]
// One block = 64 rows; 4 waves x 16 rows; layer-1 output kept in LDS (swizzled)
// ---------------------------------------------------------------------------
__global__ __launch_bounds__(256) void k_mlp_f(
    const bf16* __restrict__ Hin,          // [NB][256]
    const bf16* __restrict__ WT0,          // [128][256]
    const float* __restrict__ b0,          // [128]
    const bf16* __restrict__ WT1,          // [64][128]
    const float* __restrict__ b1,          // [64]
    const float* __restrict__ wf,          // [64]
    const float* __restrict__ bf_,         // [1]
    const float* __restrict__ scale,       // null or [NB]
    float* __restrict__ outp)              // [NB]
{
    __shared__ bf16 A[64 * 64], Bb[128 * 64], H1[64 * 128];
    const int tid = threadIdx.x, lane = tid & 63, w = tid >> 6;
    const int lr = lane & 15, hi = lane >> 4;
    const int r0 = blockIdx.x * 64;
    // ---- layer 1: [64x256] @ [256x128] ----
    f32x4 acc[8] = {};
    for (int kk = 0; kk < 4; ++kk) {
        const int k0 = kk * 64;
        if (kk) __syncthreads();
#pragma unroll
        for (int p = 0; p < 2; ++p) {
            const int t = tid + p * 256;
            const int row = t >> 3, gs = ((t & 7) ^ (row & 7)) * 8;
            ld16(A + t * 8, Hin + (r0 + row) * 256 + k0 + gs);
        }
#pragma unroll
        for (int p = 0; p < 4; ++p) {
            const int t = tid + p * 256;
            const int row = t >> 3, gs = ((t & 7) ^ (row & 7)) * 8;
            ld16(Bb + t * 8, WT0 + row * 256 + k0 + gs);
        }
        __syncthreads();
#pragma unroll
        for (int ks = 0; ks < 2; ++ks) {
            const bf16x8 a = frag64(A, w * 16 + lr, ks * 4 + hi);
            bf16x8 b[8];
#pragma unroll
            for (int nb = 0; nb < 8; ++nb) b[nb] = frag64(Bb, nb * 16 + lr, ks * 4 + hi);
#pragma unroll
            for (int nb = 0; nb < 8; ++nb) acc[nb] = MFMA(a, b[nb], acc[nb]);
        }
    }
    // layer-1 epilogue -> H1 [64][128], chunk-swizzled like frag64 expects
#pragma unroll
    for (int nb = 0; nb < 8; ++nb) {
        const int col = nb * 16 + lr;
        const float bb = b0[col];
#pragma unroll
        for (int r = 0; r < 4; ++r) {
            const int rl = w * 16 + hi * 4 + r;
            float v = acc[nb][r] + bb;
            v = v > 0.0f ? v : 0.3f * v;
            H1[rl * 128 + (((col >> 3) ^ (rl & 7)) * 8) + (col & 7)] = (bf16)v;
        }
    }
    __syncthreads();
    // ---- layer 2: [64x128] @ [128x64] ----
    f32x4 acc2[4] = {};
    for (int kk = 0; kk < 2; ++kk) {
#pragma unroll
        for (int p = 0; p < 2; ++p) {
            const int t = tid + p * 256;
            const int row = t >> 3, gs = ((t & 7) ^ (row & 7)) * 8;
            ld16(Bb + t * 8, WT1 + row * 128 + kk * 64 + gs);
        }
        __syncthreads();
#pragma unroll
        for (int ks = 0; ks < 2; ++ks) {
            const int rl = w * 16 + lr;
            const int c = kk * 8 + ks * 4 + hi;           // global 16B chunk of K=128
            const bf16x8 a = *reinterpret_cast<const bf16x8*>(
                H1 + rl * 128 + ((c ^ (rl & 7)) * 8));
            bf16x8 b[4];
#pragma unroll
            for (int jj = 0; jj < 4; ++jj) b[jj] = frag64(Bb, jj * 16 + lr, ks * 4 + hi);
#pragma unroll
            for (int jj = 0; jj < 4; ++jj) acc2[jj] = MFMA(a, b[jj], acc2[jj]);
        }
        __syncthreads();
    }
    // ---- layer 3: per-row dot(64) + sigmoid (+scale), shfl reduce over lr ----
    float b1v[4], wfv[4];
#pragma unroll
    for (int jj = 0; jj < 4; ++jj) {
        b1v[jj] = b1[jj * 16 + lr];
        wfv[jj] = wf[jj * 16 + lr];
    }
    const float bfv = bf_[0];
#pragma unroll
    for (int r = 0; r < 4; ++r) {
        float p = 0.0f;
#pragma unroll
        for (int jj = 0; jj < 4; ++jj) {
            float v = acc2[jj][r] + b1v[jj];
            v = v > 0.0f ? v : 0.3f * v;
            p = fmaf(v, wfv[jj], p);
        }
        p += __shfl_xor(p, 1); p += __shfl_xor(p, 2);
        p += __shfl_xor(p, 4); p += __shfl_xor(p, 8);
        if (lr == 0) {
            const int row = r0 + w * 16 + hi * 4 + r;
            float res = sigf(p + bfv);
            if (scale) res *= scale[row];
            outp[row] = res;
        }
    }
}

// ---------------------------------------------------------------------------
extern "C" void kernel_launch(void* const* d_in, const int* in_sizes, int n_in,
                              void* d_out, int out_size, void* d_ws, size_t ws_size,
                              hipStream_t stream)
{
    const float* x         = (const float*)d_in[0];
    const float* click     = (const float*)d_in[1];
    const float* h_c       = (const float*)d_in[2];
    const float* h_v       = (const float*)d_in[3];
    const float* s_c       = (const float*)d_in[4];
    const float* s_v       = (const float*)d_in[5];
    const int*   g_prev    = (const int*)d_in[6];
    const float* Wx_c      = (const float*)d_in[7];
    const float* bx_c      = (const float*)d_in[8];
    const float* Wh_c      = (const float*)d_in[9];
    const float* Wx_v      = (const float*)d_in[10];
    const float* bx_v      = (const float*)d_in[11];
    const float* Wh_v      = (const float*)d_in[12];
    const float* W_schat_c = (const float*)d_in[13];
    const float* W_schat_v = (const float*)d_in[14];
    const float* W_svhat_v = (const float*)d_in[15];
    const float* W_svhat_c = (const float*)d_in[16];
    const float* Wpc0 = (const float*)d_in[17];
    const float* bpc0 = (const float*)d_in[18];
    const float* Wpc1 = (const float*)d_in[19];
    const float* bpc1 = (const float*)d_in[20];
    const float* Wfcc = (const float*)d_in[21];
    const float* bfcc = (const float*)d_in[22];
    const float* Wpv0 = (const float*)d_in[23];
    const float* bpv0 = (const float*)d_in[24];
    const float* Wpv1 = (const float*)d_in[25];
    const float* bpv1 = (const float*)d_in[26];
    const float* Wfcv = (const float*)d_in[27];
    const float* bfcv = (const float*)d_in[28];

    // output layout (fp32, concatenated in return order)
    float* out     = (float*)d_out;
    float* out_hcp = out;
    float* out_hvp = out + NB;
    float* out_hcn = out + 2 * NB;
    float* out_hvn = out_hcn + NB * NU;
    float* out_scn = out_hvn + NB * NU;
    float* out_svn = out_scn + NB * NU;
    float* out_gnw = out_svn + NB * NU;

    // workspace carve: gmask first (8B aligned), then bf16 buffers
    unsigned long long* gmask64 = (unsigned long long*)d_ws;   // 131072 u64 = 1 MB
    const unsigned* gmask32 = (const unsigned*)d_ws;
    bf16* w = (bf16*)d_ws + 524288;                            // skip 1 MB
    bf16* WTc    = w; w += 256 * 256;        // W_schat_c^T
    bf16* WTv    = w; w += 256 * 256;        // W_schat_v^T
    bf16* Wsv    = w; w += 256 * 512;        // [W_svhat_v ; W_svhat_c]^T concat-K
    bf16* WT_pc0 = w; w += 128 * 256;
    bf16* WT_pv0 = w; w += 128 * 256;
    bf16* WT_pc1 = w; w += 64 * 128;
    bf16* WT_pv1 = w; w += 64 * 128;
    bf16* WgT_c  = w; w += 4 * 256 * 512;
    bf16* WgT_v  = w; w += 4 * 256 * 512;
    bf16* xs     = w; w += NB * 512;         // [x_bf | s_hat] (both branches)
    bf16* hv_cat = w; w += NB * 512;         // [h_v_bf | click-masked h_c_n]
    bf16* buf256 = w; w += NB * 256;         // h_c_bf -> hcnb -> hvnb (aliased)

    // --- weight prep jobs ---
    TrJobs J;
    int j = 0;
    J.src[j] = W_schat_c; J.dst[j] = WTc; J.R[j] = 256; J.C[j] = 256; J.dstr[j] = 256; ++j;
    J.src[j] = W_schat_v; J.dst[j] = WTv; J.R[j] = 256; J.C[j] = 256; J.dstr[j] = 256; ++j;
    J.src[j] = W_svhat_v; J.dst[j] = Wsv;       J.R[j] = 256; J.C[j] = 256; J.dstr[j] = 512; ++j;
    J.src[j] = W_svhat_c; J.dst[j] = Wsv + 256; J.R[j] = 256; J.C[j] = 256; J.dstr[j] = 512; ++j;
    J.src[j] = Wpc0; J.dst[j] = WT_pc0; J.R[j] = 256; J.C[j] = 128; J.dstr[j] = 256; ++j;
    J.src[j] = Wpv0; J.dst[j] = WT_pv0; J.R[j] = 256; J.C[j] = 128; J.dstr[j] = 256; ++j;
    J.src[j] = Wpc1; J.dst[j] = WT_pc1; J.R[j] = 128; J.C[j] = 64;  J.dstr[j] = 128; ++j;
    J.src[j] = Wpv1; J.dst[j] = WT_pv1; J.R[j] = 128; J.C[j] = 64;  J.dstr[j] = 128; ++j;
    for (int g = 0; g < 4; ++g) {
        J.src[j] = Wx_c + g * 65536; J.dst[j] = WgT_c + g * 131072;       J.R[j] = 256; J.C[j] = 256; J.dstr[j] = 512; ++j;
        J.src[j] = Wh_c + g * 65536; J.dst[j] = WgT_c + g * 131072 + 256; J.R[j] = 256; J.C[j] = 256; J.dstr[j] = 512; ++j;
    }
    for (int g = 0; g < 4; ++g) {
        J.src[j] = Wx_v + g * 65536; J.dst[j] = WgT_v + g * 131072;       J.R[j] = 256; J.C[j] = 256; J.dstr[j] = 512; ++j;
        J.src[j] = Wh_v + g * 65536; J.dst[j] = WgT_v + g * 131072 + 256; J.R[j] = 256; J.C[j] = 256; J.dstr[j] = 512; ++j;
    }

    k_cvt<<<dim3(4096, 3), 256, 0, stream>>>(x, h_v, h_c, xs, hv_cat, buf256);
    k_pack<<<1024, 256, 0, stream>>>(g_prev, gmask64);
    k_tr<<<dim3(64, 24), dim3(32, 8), 0, stream>>>(J);

    // click branch
    k_schat_t<<<dim3(256, 4), 256, 0, stream>>>(buf256, hv_cat, WTc, WTv, gmask32, xs);
    k_gates_t<<<dim3(512, 8), 256, 0, stream>>>(xs, WgT_c, bx_c, click, gmask32, s_c,
                                                nullptr, out_scn, out_hcn, nullptr,
                                                buf256, hv_cat, 0);
    k_mlp_f<<<512, 256, 0, stream>>>(buf256, WT_pc0, bpc0, WT_pc1, bpc1,
                                     Wfcc, bfcc, nullptr, out_hcp);

    // conversion branch
    k_svhat_t<<<dim3(256, 2), 256, 0, stream>>>(hv_cat, Wsv, xs);
    k_gates_t<<<dim3(512, 8), 256, 0, stream>>>(xs, WgT_v, bx_v, click, gmask32, s_v,
                                                h_v, out_svn, out_hvn, out_gnw,
                                                buf256, nullptr, 1);
    k_mlp_f<<<512, 256, 0, stream>>>(buf256, WT_pv0, bpv0, WT_pv1, bpv1,
                                     Wfcv, bfcv, out_hcp, out_hvp);
}

// Round 10
// 583.601 us; speedup vs baseline: 1.0637x; 1.0069x over previous
//
#include <hip/hip_runtime.h>
#include <hip/hip_bf16.h>
#include <math.h>

typedef __bf16 bf16;
typedef __bf16 bf16x8 __attribute__((ext_vector_type(8)));
typedef float  f32x4  __attribute__((ext_vector_type(4)));

#define NB 32768   // batch
#define NU 256     // units (= D)

#define MFMA(a,b,c) __builtin_amdgcn_mfma_f32_16x16x32_bf16((a),(b),(c),0,0,0)

// fast activations: v_rcp + v_exp based (absmax headroom is ~2^-5, these are ~1ulp)
static __device__ __forceinline__ float sigf(float x) {
    return __builtin_amdgcn_rcpf(1.0f + __expf(-x));
}
static __device__ __forceinline__ float tanh_(float x) {
    return fmaf(2.0f, sigf(2.0f * x), -1.0f);   // tanh = 2*sigmoid(2x) - 1
}

// async global->LDS, 16 B per lane. LDS dest must be thread-contiguous
// (base + tid*16); global src is per-lane arbitrary (16B-aligned).
static __device__ __forceinline__ void ld16(bf16* l, const bf16* g) {
    __builtin_amdgcn_global_load_lds(
        (const __attribute__((address_space(1))) void*)g,
        (__attribute__((address_space(3))) void*)l, 16, 0, 0);
}

// Swizzled LDS tile [rows][64] bf16 (128 B/row, 8x 16B chunks).
// Global chunk kc is stored at LDS slot kc^(row&7) (staged via pre-swizzled
// global source address; LDS dest stays linear). 16 lanes reading the same kc
// across consecutive rows then hit 8 distinct 4-bank columns -> conflict-free.
static __device__ __forceinline__ bf16x8 frag64(const bf16* buf, int row, int kc) {
    return *reinterpret_cast<const bf16x8*>(buf + row * 64 + ((kc ^ (row & 7)) * 8));
}

// ---------------------------------------------------------------------------
// fp32 -> bf16 activation conversion. job 0: x -> xs[:,0:256] (stride 512)
// job 1: h_v -> hv_cat[:,0:256] (stride 512); job 2: h_c -> buf256 (stride 256)
// ---------------------------------------------------------------------------
__global__ void k_cvt(const float* __restrict__ x, const float* __restrict__ h_v,
                      const float* __restrict__ h_c,
                      bf16* __restrict__ xs, bf16* __restrict__ hv_cat,
                      bf16* __restrict__ hcb)
{
    const int j = blockIdx.y;
    const int gid = blockIdx.x * 256 + threadIdx.x;   // 8-element index
    const int row = gid >> 5, col = (gid & 31) * 8;
    const float* src = (j == 0) ? x : (j == 1) ? h_v : h_c;
    bf16* dst; int stride;
    if (j == 0)      { dst = xs;     stride = 512; }
    else if (j == 1) { dst = hv_cat; stride = 512; }
    else             { dst = hcb;    stride = 256; }
    const f32x4* s4 = reinterpret_cast<const f32x4*>(src + row * 256 + col);
    const f32x4 a = s4[0], b = s4[1];
    bf16x8 o;
    o[0] = (bf16)a[0]; o[1] = (bf16)a[1]; o[2] = (bf16)a[2]; o[3] = (bf16)a[3];
    o[4] = (bf16)b[0]; o[5] = (bf16)b[1]; o[6] = (bf16)b[2]; o[7] = (bf16)b[3];
    *reinterpret_cast<bf16x8*>(dst + row * stride + col) = o;
}

// ---------------------------------------------------------------------------
// pack g_prev>0 into a bitmask: 33.5 MB int32 -> 1 MB (read by schat + gates)
// ---------------------------------------------------------------------------
__global__ void k_pack(const int* __restrict__ g, unsigned long long* __restrict__ m)
{
    const int tid0 = blockIdx.x * 256 + threadIdx.x;
#pragma unroll
    for (int it = 0; it < 32; ++it) {
        const int i = tid0 + it * (1024 * 256);
        const unsigned long long b = __ballot(g[i] > 0);
        if ((threadIdx.x & 63) == 0) m[i >> 6] = b;
    }
}

// ---------------------------------------------------------------------------
// Tiled transpose: dst[c*dstr + r] = (bf16)src[r*C + c]  (fp32 src)
// 24 jobs; 32x32 tiles; block (32,8)
// ---------------------------------------------------------------------------
struct TrJobs {
    const float* src[24];
    bf16*        dst[24];
    int R[24], C[24], dstr[24];
};

__global__ void k_tr(TrJobs J) {
    __shared__ float tile[32][33];
    const int j = blockIdx.y;
    const int R = J.R[j], C = J.C[j], dstr = J.dstr[j];
    const int tilesC = C >> 5;
    const int tr = blockIdx.x / tilesC, tc = blockIdx.x % tilesC;
    if (tr >= (R >> 5)) return;
    const int r0 = tr * 32, c0 = tc * 32;
    const int tx = threadIdx.x, ty = threadIdx.y;
    const float* src = J.src[j];
    bf16* dst = J.dst[j];
#pragma unroll
    for (int i = 0; i < 4; ++i)
        tile[ty + 8 * i][tx] = src[(r0 + ty + 8 * i) * C + c0 + tx];
    __syncthreads();
#pragma unroll
    for (int i = 0; i < 4; ++i)
        dst[(c0 + ty + 8 * i) * dstr + r0 + tx] = (bf16)tile[tx][ty + 8 * i];
}

// ---------------------------------------------------------------------------
// s_c_hat = where(g_prev>0, h_v@Wv, h_c@Wc) -> xs[:,256:512] (bf16)
// dual GEMM, REGISTER-DIET tile (r9-validated shape): block 64 rows x 64 cols,
// 4 waves each 16x64; acc1[4]+acc2[4] = 32 AGPR; K=256, BK=64, swizzled LDS.
// ---------------------------------------------------------------------------
__global__ __launch_bounds__(256) void k_schat_t(
    const bf16* __restrict__ hc, const bf16* __restrict__ hvcat,
    const bf16* __restrict__ WTc, const bf16* __restrict__ WTv,
    const unsigned* __restrict__ gmask, bf16* __restrict__ xs)
{
    __shared__ bf16 A1[64 * 64], A2[64 * 64], B1[64 * 64], B2[64 * 64];  // 32 KB
    const int tid = threadIdx.x, lane = tid & 63, w = tid >> 6;
    const int lr = lane & 15, hi = lane >> 4;
    const int r0 = blockIdx.x * 64, c0 = blockIdx.y * 64;
    f32x4 acc1[4] = {}, acc2[4] = {};
    for (int kk = 0; kk < 4; ++kk) {
        const int k0 = kk * 64;
        if (kk) __syncthreads();
#pragma unroll
        for (int p = 0; p < 2; ++p) {
            const int t = tid + p * 256;
            const int row = t >> 3, gs = ((t & 7) ^ (row & 7)) * 8;
            ld16(A1 + t * 8, hc    + (r0 + row) * 256 + k0 + gs);
            ld16(A2 + t * 8, hvcat + (r0 + row) * 512 + k0 + gs);
            ld16(B1 + t * 8, WTc   + (c0 + row) * 256 + k0 + gs);
            ld16(B2 + t * 8, WTv   + (c0 + row) * 256 + k0 + gs);
        }
        __syncthreads();
#pragma unroll
        for (int ks = 0; ks < 2; ++ks) {
            const bf16x8 a1 = frag64(A1, w * 16 + lr, ks * 4 + hi);
            const bf16x8 a2 = frag64(A2, w * 16 + lr, ks * 4 + hi);
            bf16x8 b1[4], b2[4];
#pragma unroll
            for (int jj = 0; jj < 4; ++jj) {
                b1[jj] = frag64(B1, jj * 16 + lr, ks * 4 + hi);
                b2[jj] = frag64(B2, jj * 16 + lr, ks * 4 + hi);
            }
#pragma unroll
            for (int jj = 0; jj < 4; ++jj) {
                acc1[jj] = MFMA(a1, b1[jj], acc1[jj]);
                acc2[jj] = MFMA(a2, b2[jj], acc2[jj]);
            }
        }
    }
#pragma unroll
    for (int jj = 0; jj < 4; ++jj)
#pragma unroll
        for (int r = 0; r < 4; ++r) {
            const int row = r0 + w * 16 + hi * 4 + r;
            const int col = c0 + jj * 16 + lr;
            const bool gp = (gmask[row * 8 + (col >> 5)] >> (col & 31)) & 1;
            xs[row * 512 + 256 + col] = (bf16)(gp ? acc2[jj][r] : acc1[jj][r]);
        }
}

// ---------------------------------------------------------------------------
// s_v_hat = hv_cat @ Wsv -> xs[:,256:512]; K=512, REGISTER-DIET tile:
// block 64 rows x 128 cols, 4 waves each 16x128; acc[8] = 32 AGPR; BK=64.
// (byte-identical structure to the r9-validated gates shape)
// ---------------------------------------------------------------------------
__global__ __launch_bounds__(256) void k_svhat_t(
    const bf16* __restrict__ hvcat, const bf16* __restrict__ Wsv,
    bf16* __restrict__ xs)
{
    __shared__ bf16 A[64 * 64], B[128 * 64];       // 8 KB + 16 KB
    const int tid = threadIdx.x, lane = tid & 63, w = tid >> 6;
    const int lr = lane & 15, hi = lane >> 4;
    const int r0 = blockIdx.x * 64, c0 = blockIdx.y * 128;
    f32x4 acc[8] = {};
    for (int kk = 0; kk < 8; ++kk) {
        const int k0 = kk * 64;
        if (kk) __syncthreads();
#pragma unroll
        for (int p = 0; p < 2; ++p) {
            const int t = tid + p * 256;
            const int row = t >> 3, gs = ((t & 7) ^ (row & 7)) * 8;
            ld16(A + t * 8, hvcat + (r0 + row) * 512 + k0 + gs);
        }
#pragma unroll
        for (int p = 0; p < 4; ++p) {
            const int t = tid + p * 256;
            const int row = t >> 3, gs = ((t & 7) ^ (row & 7)) * 8;
            ld16(B + t * 8, Wsv + (c0 + row) * 512 + k0 + gs);
        }
        __syncthreads();
#pragma unroll
        for (int ks = 0; ks < 2; ++ks) {
            const bf16x8 a = frag64(A, w * 16 + lr, ks * 4 + hi);
            bf16x8 b[8];
#pragma unroll
            for (int jj = 0; jj < 8; ++jj) b[jj] = frag64(B, jj * 16 + lr, ks * 4 + hi);
#pragma unroll
            for (int jj = 0; jj < 8; ++jj) acc[jj] = MFMA(a, b[jj], acc[jj]);
        }
    }
#pragma unroll
    for (int jj = 0; jj < 8; ++jj)
#pragma unroll
        for (int r = 0; r < 4; ++r) {
            const int row = r0 + w * 16 + hi * 4 + r;
            const int col = c0 + jj * 16 + lr;
            xs[row * 512 + 256 + col] = (bf16)acc[jj][r];
        }
}

// ---------------------------------------------------------------------------
// Gates GEMM + cell update. A = xs (K=512, BK=64); B tile = 4 gates x 32 u.
// REGISTER-DIET tile: block = 64 rows x 128 cols, 4 waves each 16 rows.
// acc[8] = 32 AGPRs -> ~5-6 waves/SIMD potential; measured r9: occ 38%,
// dur 106.7 us (was 118 at 3 waves/SIMD). Same r2 staging/swizzle.
// mode 0 = click branch, mode 1 = conversion branch.
// ---------------------------------------------------------------------------
__global__ __launch_bounds__(256) void k_gates_t(
    const bf16* __restrict__ xs, const bf16* __restrict__ WgT,
    const float* __restrict__ bx, const float* __restrict__ click,
    const unsigned* __restrict__ gmask, const float* __restrict__ s_prev,
    const float* __restrict__ h_prev,
    float* __restrict__ out_s, float* __restrict__ out_h,
    float* __restrict__ out_g, bf16* __restrict__ hnb,
    bf16* __restrict__ hmask_dst, int mode)
{
    __shared__ bf16 A[64 * 64], B[128 * 64];       // 8 KB + 16 KB
    const int tid = threadIdx.x, lane = tid & 63, w = tid >> 6;
    const int lr = lane & 15, hi = lane >> 4;
    const int r0 = blockIdx.x * 64, u0 = blockIdx.y * 32;
    f32x4 acc[8] = {};
    for (int kk = 0; kk < 8; ++kk) {
        const int k0 = kk * 64;
        if (kk) __syncthreads();
#pragma unroll
        for (int p = 0; p < 2; ++p) {
            const int t = tid + p * 256;
            const int row = t >> 3, gs = ((t & 7) ^ (row & 7)) * 8;
            ld16(A + t * 8, xs + (r0 + row) * 512 + k0 + gs);
        }
#pragma unroll
        for (int p = 0; p < 4; ++p) {
            const int t = tid + p * 256;
            const int row = t >> 3, gs = ((t & 7) ^ (row & 7)) * 8;
            const int g = row >> 5, ul = row & 31;
            ld16(B + t * 8, WgT + (g * 256 + u0 + ul) * 512 + k0 + gs);
        }
        __syncthreads();
#pragma unroll
        for (int ks = 0; ks < 2; ++ks) {
            const bf16x8 a = frag64(A, w * 16 + lr, ks * 4 + hi);
            bf16x8 b[8];
#pragma unroll
            for (int nb = 0; nb < 8; ++nb) b[nb] = frag64(B, nb * 16 + lr, ks * 4 + hi);
#pragma unroll
            for (int nb = 0; nb < 8; ++nb) acc[nb] = MFMA(a, b[nb], acc[nb]);
        }
    }
    // epilogue: gate gg lives in acc[gg*2 + uh]
    const int u0b = u0 >> 5;
    float bfv[2], biv[2], bov[2], bgv[2];
#pragma unroll
    for (int uh = 0; uh < 2; ++uh) {
        const int u = u0 + uh * 16 + lr;
        bfv[uh] = bx[u];       biv[uh] = bx[256 + u];
        bov[uh] = bx[512 + u]; bgv[uh] = bx[768 + u];
    }
#pragma unroll
    for (int r = 0; r < 4; ++r) {
        const int row = r0 + w * 16 + hi * 4 + r;
        const float ck = click[row];
        const unsigned mw = (mode == 0) ? gmask[row * 8 + u0b] : 0u;
#pragma unroll
        for (int uh = 0; uh < 2; ++uh) {
            const int u = u0 + uh * 16 + lr;
            const int o = row * 256 + u;
            const float f  = sigf(acc[0 + uh][r] + bfv[uh]);
            const float ii = sigf(acc[2 + uh][r] + biv[uh]);
            const float oo = sigf(acc[4 + uh][r] + bov[uh]);
            const float gg = tanh_(acc[6 + uh][r] + bgv[uh]);
            if (mode == 0) {
                const bool gp = (mw >> (u & 31)) & 1;
                const float sn = ii * gg + (gp ? 0.0f : f * s_prev[o]);
                const float hn = oo * tanh_(sn);
                out_s[o] = sn;
                out_h[o] = hn;
                hnb[o]   = (bf16)hn;
                hmask_dst[row * 512 + 256 + u] =
                    (ck >= 0.5f) ? (bf16)hn : (bf16)0.0f;
            } else {
                const bool m = ck >= 0.5f;
                const float sv = s_prev[o];
                const float sn = m ? (f * sv + ii * gg) : sv;
                const float hn = m ? (oo * tanh_(sn)) : h_prev[o];
                out_s[o] = sn;
                out_h[o] = hn;
                out_g[o] = m ? 1.0f : 0.0f;
                hnb[o]   = (bf16)hn;
            }
        }
    }
}

// ---------------------------------------------------------------------------
// Fused MLP: leaky(H@W0+b0) -> leaky(@W1+b1) -> sigmoid(dot(wf)+bf) [*scale]
// One block = 64 rows; 4 waves x 16 rows; layer-1 output kept in LDS (swizzled)
// ---------------------------------------------------------------------------
__global__ __launch_bounds__(256) void k_mlp_f(
    const bf16* __restrict__ Hin,          // [NB][256]
    const bf16* __restrict__ WT0,          // [128][256]
    const float* __restrict__ b0,          // [128]
    const bf16* __restrict__ WT1,          // [64][128]
    const float* __restrict__ b1,          // [64]
    const float* __restrict__ wf,          // [64]
    const float* __restrict__ bf_,         // [1]
    const float* __restrict__ scale,       // null or [NB]
    float* __restrict__ outp)              // [NB]
{
    __shared__ bf16 A[64 * 64], Bb[128 * 64], H1[64 * 128];
    const int tid = threadIdx.x, lane = tid & 63, w = tid >> 6;
    const int lr = lane & 15, hi = lane >> 4;
    const int r0 = blockIdx.x * 64;
    // ---- layer 1: [64x256] @ [256x128] ----
    f32x4 acc[8] = {};
    for (int kk = 0; kk < 4; ++kk) {
        const int k0 = kk * 64;
        if (kk) __syncthreads();
#pragma unroll
        for (int p = 0; p < 2; ++p) {
            const int t = tid + p * 256;
            const int row = t >> 3, gs = ((t & 7) ^ (row & 7)) * 8;
            ld16(A + t * 8, Hin + (r0 + row) * 256 + k0 + gs);
        }
#pragma unroll
        for (int p = 0; p < 4; ++p) {
            const int t = tid + p * 256;
            const int row = t >> 3, gs = ((t & 7) ^ (row & 7)) * 8;
            ld16(Bb + t * 8, WT0 + row * 256 + k0 + gs);
        }
        __syncthreads();
#pragma unroll
        for (int ks = 0; ks < 2; ++ks) {
            const bf16x8 a = frag64(A, w * 16 + lr, ks * 4 + hi);
            bf16x8 b[8];
#pragma unroll
            for (int nb = 0; nb < 8; ++nb) b[nb] = frag64(Bb, nb * 16 + lr, ks * 4 + hi);
#pragma unroll
            for (int nb = 0; nb < 8; ++nb) acc[nb] = MFMA(a, b[nb], acc[nb]);
        }
    }
    // layer-1 epilogue -> H1 [64][128], chunk-swizzled like frag64 expects
#pragma unroll
    for (int nb = 0; nb < 8; ++nb) {
        const int col = nb * 16 + lr;
        const float bb = b0[col];
#pragma unroll
        for (int r = 0; r < 4; ++r) {
            const int rl = w * 16 + hi * 4 + r;
            float v = acc[nb][r] + bb;
            v = v > 0.0f ? v : 0.3f * v;
            H1[rl * 128 + (((col >> 3) ^ (rl & 7)) * 8) + (col & 7)] = (bf16)v;
        }
    }
    __syncthreads();
    // ---- layer 2: [64x128] @ [128x64] ----
    f32x4 acc2[4] = {};
    for (int kk = 0; kk < 2; ++kk) {
#pragma unroll
        for (int p = 0; p < 2; ++p) {
            const int t = tid + p * 256;
            const int row = t >> 3, gs = ((t & 7) ^ (row & 7)) * 8;
            ld16(Bb + t * 8, WT1 + row * 128 + kk * 64 + gs);
        }
        __syncthreads();
#pragma unroll
        for (int ks = 0; ks < 2; ++ks) {
            const int rl = w * 16 + lr;
            const int c = kk * 8 + ks * 4 + hi;           // global 16B chunk of K=128
            const bf16x8 a = *reinterpret_cast<const bf16x8*>(
                H1 + rl * 128 + ((c ^ (rl & 7)) * 8));
            bf16x8 b[4];
#pragma unroll
            for (int jj = 0; jj < 4; ++jj) b[jj] = frag64(Bb, jj * 16 + lr, ks * 4 + hi);
#pragma unroll
            for (int jj = 0; jj < 4; ++jj) acc2[jj] = MFMA(a, b[jj], acc2[jj]);
        }
        __syncthreads();
    }
    // ---- layer 3: per-row dot(64) + sigmoid (+scale), shfl reduce over lr ----
    float b1v[4], wfv[4];
#pragma unroll
    for (int jj = 0; jj < 4; ++jj) {
        b1v[jj] = b1[jj * 16 + lr];
        wfv[jj] = wf[jj * 16 + lr];
    }
    const float bfv = bf_[0];
#pragma unroll
    for (int r = 0; r < 4; ++r) {
        float p = 0.0f;
#pragma unroll
        for (int jj = 0; jj < 4; ++jj) {
            float v = acc2[jj][r] + b1v[jj];
            v = v > 0.0f ? v : 0.3f * v;
            p = fmaf(v, wfv[jj], p);
        }
        p += __shfl_xor(p, 1); p += __shfl_xor(p, 2);
        p += __shfl_xor(p, 4); p += __shfl_xor(p, 8);
        if (lr == 0) {
            const int row = r0 + w * 16 + hi * 4 + r;
            float res = sigf(p + bfv);
            if (scale) res *= scale[row];
            outp[row] = res;
        }
    }
}

// ---------------------------------------------------------------------------
extern "C" void kernel_launch(void* const* d_in, const int* in_sizes, int n_in,
                              void* d_out, int out_size, void* d_ws, size_t ws_size,
                              hipStream_t stream)
{
    const float* x         = (const float*)d_in[0];
    const float* click     = (const float*)d_in[1];
    const float* h_c       = (const float*)d_in[2];
    const float* h_v       = (const float*)d_in[3];
    const float* s_c       = (const float*)d_in[4];
    const float* s_v       = (const float*)d_in[5];
    const int*   g_prev    = (const int*)d_in[6];
    const float* Wx_c      = (const float*)d_in[7];
    const float* bx_c      = (const float*)d_in[8];
    const float* Wh_c      = (const float*)d_in[9];
    const float* Wx_v      = (const float*)d_in[10];
    const float* bx_v      = (const float*)d_in[11];
    const float* Wh_v      = (const float*)d_in[12];
    const float* W_schat_c = (const float*)d_in[13];
    const float* W_schat_v = (const float*)d_in[14];
    const float* W_svhat_v = (const float*)d_in[15];
    const float* W_svhat_c = (const float*)d_in[16];
    const float* Wpc0 = (const float*)d_in[17];
    const float* bpc0 = (const float*)d_in[18];
    const float* Wpc1 = (const float*)d_in[19];
    const float* bpc1 = (const float*)d_in[20];
    const float* Wfcc = (const float*)d_in[21];
    const float* bfcc = (const float*)d_in[22];
    const float* Wpv0 = (const float*)d_in[23];
    const float* bpv0 = (const float*)d_in[24];
    const float* Wpv1 = (const float*)d_in[25];
    const float* bpv1 = (const float*)d_in[26];
    const float* Wfcv = (const float*)d_in[27];
    const float* bfcv = (const float*)d_in[28];

    // output layout (fp32, concatenated in return order)
    float* out     = (float*)d_out;
    float* out_hcp = out;
    float* out_hvp = out + NB;
    float* out_hcn = out + 2 * NB;
    float* out_hvn = out_hcn + NB * NU;
    float* out_scn = out_hvn + NB * NU;
    float* out_svn = out_scn + NB * NU;
    float* out_gnw = out_svn + NB * NU;

    // workspace carve: gmask first (8B aligned), then bf16 buffers
    unsigned long long* gmask64 = (unsigned long long*)d_ws;   // 131072 u64 = 1 MB
    const unsigned* gmask32 = (const unsigned*)d_ws;
    bf16* w = (bf16*)d_ws + 524288;                            // skip 1 MB
    bf16* WTc    = w; w += 256 * 256;        // W_schat_c^T
    bf16* WTv    = w; w += 256 * 256;        // W_schat_v^T
    bf16* Wsv    = w; w += 256 * 512;        // [W_svhat_v ; W_svhat_c]^T concat-K
    bf16* WT_pc0 = w; w += 128 * 256;
    bf16* WT_pv0 = w; w += 128 * 256;
    bf16* WT_pc1 = w; w += 64 * 128;
    bf16* WT_pv1 = w; w += 64 * 128;
    bf16* WgT_c  = w; w += 4 * 256 * 512;
    bf16* WgT_v  = w; w += 4 * 256 * 512;
    bf16* xs     = w; w += NB * 512;         // [x_bf | s_hat] (both branches)
    bf16* hv_cat = w; w += NB * 512;         // [h_v_bf | click-masked h_c_n]
    bf16* buf256 = w; w += NB * 256;         // h_c_bf -> hcnb -> hvnb (aliased)

    // --- weight prep jobs ---
    TrJobs J;
    int j = 0;
    J.src[j] = W_schat_c; J.dst[j] = WTc; J.R[j] = 256; J.C[j] = 256; J.dstr[j] = 256; ++j;
    J.src[j] = W_schat_v; J.dst[j] = WTv; J.R[j] = 256; J.C[j] = 256; J.dstr[j] = 256; ++j;
    J.src[j] = W_svhat_v; J.dst[j] = Wsv;       J.R[j] = 256; J.C[j] = 256; J.dstr[j] = 512; ++j;
    J.src[j] = W_svhat_c; J.dst[j] = Wsv + 256; J.R[j] = 256; J.C[j] = 256; J.dstr[j] = 512; ++j;
    J.src[j] = Wpc0; J.dst[j] = WT_pc0; J.R[j] = 256; J.C[j] = 128; J.dstr[j] = 256; ++j;
    J.src[j] = Wpv0; J.dst[j] = WT_pv0; J.R[j] = 256; J.C[j] = 128; J.dstr[j] = 256; ++j;
    J.src[j] = Wpc1; J.dst[j] = WT_pc1; J.R[j] = 128; J.C[j] = 64;  J.dstr[j] = 128; ++j;
    J.src[j] = Wpv1; J.dst[j] = WT_pv1; J.R[j] = 128; J.C[j] = 64;  J.dstr[j] = 128; ++j;
    for (int g = 0; g < 4; ++g) {
        J.src[j] = Wx_c + g * 65536; J.dst[j] = WgT_c + g * 131072;       J.R[j] = 256; J.C[j] = 256; J.dstr[j] = 512; ++j;
        J.src[j] = Wh_c + g * 65536; J.dst[j] = WgT_c + g * 131072 + 256; J.R[j] = 256; J.C[j] = 256; J.dstr[j] = 512; ++j;
    }
    for (int g = 0; g < 4; ++g) {
        J.src[j] = Wx_v + g * 65536; J.dst[j] = WgT_v + g * 131072;       J.R[j] = 256; J.C[j] = 256; J.dstr[j] = 512; ++j;
        J.src[j] = Wh_v + g * 65536; J.dst[j] = WgT_v + g * 131072 + 256; J.R[j] = 256; J.C[j] = 256; J.dstr[j] = 512; ++j;
    }

    k_cvt<<<dim3(4096, 3), 256, 0, stream>>>(x, h_v, h_c, xs, hv_cat, buf256);
    k_pack<<<1024, 256, 0, stream>>>(g_prev, gmask64);
    k_tr<<<dim3(64, 24), dim3(32, 8), 0, stream>>>(J);

    // click branch
    k_schat_t<<<dim3(512, 4), 256, 0, stream>>>(buf256, hv_cat, WTc, WTv, gmask32, xs);
    k_gates_t<<<dim3(512, 8), 256, 0, stream>>>(xs, WgT_c, bx_c, click, gmask32, s_c,
                                                nullptr, out_scn, out_hcn, nullptr,
                                                buf256, hv_cat, 0);
    k_mlp_f<<<512, 256, 0, stream>>>(buf256, WT_pc0, bpc0, WT_pc1, bpc1,
                                     Wfcc, bfcc, nullptr, out_hcp);

    // conversion branch
    k_svhat_t<<<dim3(512, 2), 256, 0, stream>>>(hv_cat, Wsv, xs);
    k_gates_t<<<dim3(512, 8), 256, 0, stream>>>(xs, WgT_v, bx_v, click, gmask32, s_v,
                                                h_v, out_svn, out_hvn, out_gnw,
                                                buf256, nullptr, 1);
    k_mlp_f<<<512, 256, 0, stream>>>(buf256, WT_pv0, bpv0, WT_pv1, bpv1,
                                     Wfcv, bfcv, out_hcp, out_hvp);
}

// Round 12
// 581.849 us; speedup vs baseline: 1.0669x; 1.0030x over previous
//
#include <hip/hip_runtime.h>
#include <hip/hip_bf16.h>
#include <math.h>

typedef __bf16 bf16;
typedef __bf16 bf16x8 __attribute__((ext_vector_type(8)));
typedef float  f32x4  __attribute__((ext_vector_type(4)));

#define NB 32768   // batch
#define NU 256     // units (= D)

#define MFMA(a,b,c) __builtin_amdgcn_mfma_f32_16x16x32_bf16((a),(b),(c),0,0,0)

// fast activations: v_rcp + v_exp based (absmax headroom is ~2^-5, these are ~1ulp)
static __device__ __forceinline__ float sigf(float x) {
    return __builtin_amdgcn_rcpf(1.0f + __expf(-x));
}
static __device__ __forceinline__ float tanh_(float x) {
    return fmaf(2.0f, sigf(2.0f * x), -1.0f);   // tanh = 2*sigmoid(2x) - 1
}

// async global->LDS, 16 B per lane. LDS dest must be thread-contiguous
// (base + tid*16); global src is per-lane arbitrary (16B-aligned).
static __device__ __forceinline__ void ld16(bf16* l, const bf16* g) {
    __builtin_amdgcn_global_load_lds(
        (const __attribute__((address_space(1))) void*)g,
        (__attribute__((address_space(3))) void*)l, 16, 0, 0);
}

// Swizzled LDS tile [rows][64] bf16 (128 B/row, 8x 16B chunks).
// Global chunk kc is stored at LDS slot kc^(row&7) (staged via pre-swizzled
// global source address; LDS dest stays linear). 16 lanes reading the same kc
// across consecutive rows then hit 8 distinct 4-bank columns -> conflict-free.
static __device__ __forceinline__ bf16x8 frag64(const bf16* buf, int row, int kc) {
    return *reinterpret_cast<const bf16x8*>(buf + row * 64 + ((kc ^ (row & 7)) * 8));
}

// ---------------------------------------------------------------------------
// Fused prologue: all independent prep work in ONE launch (removes 2 full
// pipeline drains + launch gaps; tiny tr/pack jobs ride inside cvt occupancy).
//  y=0: x    -> xs[:,0:256]      (bf16, stride 512)
//  y=1: h_v  -> hv_cat[:,0:256]  (bf16, stride 512)
//  y=2: h_c  -> buf256           (bf16, stride 256)
//  y=3: 24 transpose jobs (x = job*64 + tile), 32x32 tiles, fp32 -> bf16^T
//  y=4: pack g_prev>0 bitmask (x < 1024)
// ---------------------------------------------------------------------------
struct TrJobs {
    const float* src[24];
    bf16*        dst[24];
    int R[24], C[24], dstr[24];
};

__global__ void k_pre(const float* __restrict__ x, const float* __restrict__ h_v,
                      const float* __restrict__ h_c,
                      bf16* __restrict__ xs, bf16* __restrict__ hv_cat,
                      bf16* __restrict__ hcb,
                      const int* __restrict__ g, unsigned long long* __restrict__ m,
                      TrJobs J)
{
    __shared__ float tile[32][33];
    const int yy = blockIdx.y;
    if (yy < 3) {
        // fp32 -> bf16 conversion jobs
        const int gid = blockIdx.x * 256 + threadIdx.x;   // 8-element index
        const int row = gid >> 5, col = (gid & 31) * 8;
        const float* src = (yy == 0) ? x : (yy == 1) ? h_v : h_c;
        bf16* dst; int stride;
        if (yy == 0)      { dst = xs;     stride = 512; }
        else if (yy == 1) { dst = hv_cat; stride = 512; }
        else              { dst = hcb;    stride = 256; }
        const f32x4* s4 = reinterpret_cast<const f32x4*>(src + row * 256 + col);
        const f32x4 a = s4[0], b = s4[1];
        bf16x8 o;
        o[0] = (bf16)a[0]; o[1] = (bf16)a[1]; o[2] = (bf16)a[2]; o[3] = (bf16)a[3];
        o[4] = (bf16)b[0]; o[5] = (bf16)b[1]; o[6] = (bf16)b[2]; o[7] = (bf16)b[3];
        *reinterpret_cast<bf16x8*>(dst + row * stride + col) = o;
    } else if (yy == 3) {
        // tiled transpose jobs
        const int bx = blockIdx.x;
        if (bx >= 24 * 64) return;
        const int j = bx >> 6, tl = bx & 63;
        const int R = J.R[j], C = J.C[j], dstr = J.dstr[j];
        const int tilesC = C >> 5;
        const int tr = tl / tilesC, tc = tl % tilesC;
        if (tr >= (R >> 5)) return;
        const int r0 = tr * 32, c0 = tc * 32;
        const int tx = threadIdx.x & 31, ty = threadIdx.x >> 5;   // (32,8)
        const float* src = J.src[j];
        bf16* dst = J.dst[j];
#pragma unroll
        for (int i = 0; i < 4; ++i)
            tile[ty + 8 * i][tx] = src[(r0 + ty + 8 * i) * C + c0 + tx];
        __syncthreads();
#pragma unroll
        for (int i = 0; i < 4; ++i)
            dst[(c0 + ty + 8 * i) * dstr + r0 + tx] = (bf16)tile[tx][ty + 8 * i];
    } else if (yy == 4) {
        // bitmask pack: 33.5 MB int32 -> 1 MB
        if (blockIdx.x >= 1024) return;
        const int tid0 = blockIdx.x * 256 + threadIdx.x;
#pragma unroll
        for (int it = 0; it < 32; ++it) {
            const int i = tid0 + it * (1024 * 256);
            const unsigned long long b = __ballot(g[i] > 0);
            if ((threadIdx.x & 63) == 0) m[i >> 6] = b;
        }
    }
}

// ---------------------------------------------------------------------------
// s_c_hat = where(g_prev>0, h_v@Wv, h_c@Wc) -> xs[:,256:512] (bf16)
// dual GEMM, REGISTER-DIET tile (r9-validated shape): block 64 rows x 64 cols,
// 4 waves each 16x64; acc1[4]+acc2[4] = 32 AGPR; K=256, BK=64, swizzled LDS.
// ---------------------------------------------------------------------------
__global__ __launch_bounds__(256) void k_schat_t(
    const bf16* __restrict__ hc, const bf16* __restrict__ hvcat,
    const bf16* __restrict__ WTc, const bf16* __restrict__ WTv,
    const unsigned* __restrict__ gmask, bf16* __restrict__ xs)
{
    __shared__ bf16 A1[64 * 64], A2[64 * 64], B1[64 * 64], B2[64 * 64];  // 32 KB
    const int tid = threadIdx.x, lane = tid & 63, w = tid >> 6;
    const int lr = lane & 15, hi = lane >> 4;
    const int r0 = blockIdx.x * 64, c0 = blockIdx.y * 64;
    f32x4 acc1[4] = {}, acc2[4] = {};
    for (int kk = 0; kk < 4; ++kk) {
        const int k0 = kk * 64;
        if (kk) __syncthreads();
#pragma unroll
        for (int p = 0; p < 2; ++p) {
            const int t = tid + p * 256;
            const int row = t >> 3, gs = ((t & 7) ^ (row & 7)) * 8;
            ld16(A1 + t * 8, hc    + (r0 + row) * 256 + k0 + gs);
            ld16(A2 + t * 8, hvcat + (r0 + row) * 512 + k0 + gs);
            ld16(B1 + t * 8, WTc   + (c0 + row) * 256 + k0 + gs);
            ld16(B2 + t * 8, WTv   + (c0 + row) * 256 + k0 + gs);
        }
        __syncthreads();
#pragma unroll
        for (int ks = 0; ks < 2; ++ks) {
            const bf16x8 a1 = frag64(A1, w * 16 + lr, ks * 4 + hi);
            const bf16x8 a2 = frag64(A2, w * 16 + lr, ks * 4 + hi);
            bf16x8 b1[4], b2[4];
#pragma unroll
            for (int jj = 0; jj < 4; ++jj) {
                b1[jj] = frag64(B1, jj * 16 + lr, ks * 4 + hi);
                b2[jj] = frag64(B2, jj * 16 + lr, ks * 4 + hi);
            }
#pragma unroll
            for (int jj = 0; jj < 4; ++jj) {
                acc1[jj] = MFMA(a1, b1[jj], acc1[jj]);
                acc2[jj] = MFMA(a2, b2[jj], acc2[jj]);
            }
        }
    }
#pragma unroll
    for (int jj = 0; jj < 4; ++jj)
#pragma unroll
        for (int r = 0; r < 4; ++r) {
            const int row = r0 + w * 16 + hi * 4 + r;
            const int col = c0 + jj * 16 + lr;
            const bool gp = (gmask[row * 8 + (col >> 5)] >> (col & 31)) & 1;
            xs[row * 512 + 256 + col] = (bf16)(gp ? acc2[jj][r] : acc1[jj][r]);
        }
}

// ---------------------------------------------------------------------------
// s_v_hat = hv_cat @ Wsv -> xs[:,256:512]; K=512, REGISTER-DIET tile:
// block 64 rows x 128 cols, 4 waves each 16x128; acc[8] = 32 AGPR; BK=64.
// ---------------------------------------------------------------------------
__global__ __launch_bounds__(256) void k_svhat_t(
    const bf16* __restrict__ hvcat, const bf16* __restrict__ Wsv,
    bf16* __restrict__ xs)
{
    __shared__ bf16 A[64 * 64], B[128 * 64];       // 8 KB + 16 KB
    const int tid = threadIdx.x, lane = tid & 63, w = tid >> 6;
    const int lr = lane & 15, hi = lane >> 4;
    const int r0 = blockIdx.x * 64, c0 = blockIdx.y * 128;
    f32x4 acc[8] = {};
    for (int kk = 0; kk < 8; ++kk) {
        const int k0 = kk * 64;
        if (kk) __syncthreads();
#pragma unroll
        for (int p = 0; p < 2; ++p) {
            const int t = tid + p * 256;
            const int row = t >> 3, gs = ((t & 7) ^ (row & 7)) * 8;
            ld16(A + t * 8, hvcat + (r0 + row) * 512 + k0 + gs);
        }
#pragma unroll
        for (int p = 0; p < 4; ++p) {
            const int t = tid + p * 256;
            const int row = t >> 3, gs = ((t & 7) ^ (row & 7)) * 8;
            ld16(B + t * 8, Wsv + (c0 + row) * 512 + k0 + gs);
        }
        __syncthreads();
#pragma unroll
        for (int ks = 0; ks < 2; ++ks) {
            const bf16x8 a = frag64(A, w * 16 + lr, ks * 4 + hi);
            bf16x8 b[8];
#pragma unroll
            for (int jj = 0; jj < 8; ++jj) b[jj] = frag64(B, jj * 16 + lr, ks * 4 + hi);
#pragma unroll
            for (int jj = 0; jj < 8; ++jj) acc[jj] = MFMA(a, b[jj], acc[jj]);
        }
    }
#pragma unroll
    for (int jj = 0; jj < 8; ++jj)
#pragma unroll
        for (int r = 0; r < 4; ++r) {
            const int row = r0 + w * 16 + hi * 4 + r;
            const int col = c0 + jj * 16 + lr;
            xs[row * 512 + 256 + col] = (bf16)acc[jj][r];
        }
}

// ---------------------------------------------------------------------------
// Gates GEMM + cell update. A = xs (K=512, BK=64); B tile = 4 gates x 32 u.
// REGISTER-DIET tile: block = 64 rows x 128 cols, 4 waves each 16 rows.
// acc[8] = 32 AGPRs; measured r9/r10: VGPR 52, occ 38%, dur 106.5 us.
// mode 0 = click branch, mode 1 = conversion branch.
// ---------------------------------------------------------------------------
__global__ __launch_bounds__(256) void k_gates_t(
    const bf16* __restrict__ xs, const bf16* __restrict__ WgT,
    const float* __restrict__ bx, const float* __restrict__ click,
    const unsigned* __restrict__ gmask, const float* __restrict__ s_prev,
    const float* __restrict__ h_prev,
    float* __restrict__ out_s, float* __restrict__ out_h,
    float* __restrict__ out_g, bf16* __restrict__ hnb,
    bf16* __restrict__ hmask_dst, int mode)
{
    __shared__ bf16 A[64 * 64], B[128 * 64];       // 8 KB + 16 KB
    const int tid = threadIdx.x, lane = tid & 63, w = tid >> 6;
    const int lr = lane & 15, hi = lane >> 4;
    const int r0 = blockIdx.x * 64, u0 = blockIdx.y * 32;
    f32x4 acc[8] = {};
    for (int kk = 0; kk < 8; ++kk) {
        const int k0 = kk * 64;
        if (kk) __syncthreads();
#pragma unroll
        for (int p = 0; p < 2; ++p) {
            const int t = tid + p * 256;
            const int row = t >> 3, gs = ((t & 7) ^ (row & 7)) * 8;
            ld16(A + t * 8, xs + (r0 + row) * 512 + k0 + gs);
        }
#pragma unroll
        for (int p = 0; p < 4; ++p) {
            const int t = tid + p * 256;
            const int row = t >> 3, gs = ((t & 7) ^ (row & 7)) * 8;
            const int g = row >> 5, ul = row & 31;
            ld16(B + t * 8, WgT + (g * 256 + u0 + ul) * 512 + k0 + gs);
        }
        __syncthreads();
#pragma unroll
        for (int ks = 0; ks < 2; ++ks) {
            const bf16x8 a = frag64(A, w * 16 + lr, ks * 4 + hi);
            bf16x8 b[8];
#pragma unroll
            for (int nb = 0; nb < 8; ++nb) b[nb] = frag64(B, nb * 16 + lr, ks * 4 + hi);
#pragma unroll
            for (int nb = 0; nb < 8; ++nb) acc[nb] = MFMA(a, b[nb], acc[nb]);
        }
    }
    // epilogue: gate gg lives in acc[gg*2 + uh]
    const int u0b = u0 >> 5;
    float bfv[2], biv[2], bov[2], bgv[2];
#pragma unroll
    for (int uh = 0; uh < 2; ++uh) {
        const int u = u0 + uh * 16 + lr;
        bfv[uh] = bx[u];       biv[uh] = bx[256 + u];
        bov[uh] = bx[512 + u]; bgv[uh] = bx[768 + u];
    }
#pragma unroll
    for (int r = 0; r < 4; ++r) {
        const int row = r0 + w * 16 + hi * 4 + r;
        const float ck = click[row];
        const unsigned mw = (mode == 0) ? gmask[row * 8 + u0b] : 0u;
#pragma unroll
        for (int uh = 0; uh < 2; ++uh) {
            const int u = u0 + uh * 16 + lr;
            const int o = row * 256 + u;
            const float f  = sigf(acc[0 + uh][r] + bfv[uh]);
            const float ii = sigf(acc[2 + uh][r] + biv[uh]);
            const float oo = sigf(acc[4 + uh][r] + bov[uh]);
            const float gg = tanh_(acc[6 + uh][r] + bgv[uh]);
            if (mode == 0) {
                const bool gp = (mw >> (u & 31)) & 1;
                const float sn = ii * gg + (gp ? 0.0f : f * s_prev[o]);
                const float hn = oo * tanh_(sn);
                out_s[o] = sn;
                out_h[o] = hn;
                hnb[o]   = (bf16)hn;
                hmask_dst[row * 512 + 256 + u] =
                    (ck >= 0.5f) ? (bf16)hn : (bf16)0.0f;
            } else {
                const bool m = ck >= 0.5f;
                const float sv = s_prev[o];
                const float sn = m ? (f * sv + ii * gg) : sv;
                const float hn = m ? (oo * tanh_(sn)) : h_prev[o];
                out_s[o] = sn;
                out_h[o] = hn;
                out_g[o] = m ? 1.0f : 0.0f;
                hnb[o]   = (bf16)hn;
            }
        }
    }
}

// ---------------------------------------------------------------------------
// Fused MLP: leaky(H@W0+b0) -> leaky(@W1+b1) -> sigmoid(dot(wf)+bf) [*scale]
// One block = 64 rows; 4 waves x 16 rows; layer-1 output kept in LDS (swizzled)
// ---------------------------------------------------------------------------
__global__ __launch_bounds__(256) void k_mlp_f(
    const bf16* __restrict__ Hin,          // [NB][256]
    const bf16* __restrict__ WT0,          // [128][256]
    const float* __restrict__ b0,          // [128]
    const bf16* __restrict__ WT1,          // [64][128]
    const float* __restrict__ b1,          // [64]
    const float* __restrict__ wf,          // [64]
    const float* __restrict__ bf_,         // [1]
    const float* __restrict__ scale,       // null or [NB]
    float* __restrict__ outp)              // [NB]
{
    __shared__ bf16 A[64 * 64], Bb[128 * 64], H1[64 * 128];
    const int tid = threadIdx.x, lane = tid & 63, w = tid >> 6;
    const int lr = lane & 15, hi = lane >> 4;
    const int r0 = blockIdx.x * 64;
    // ---- layer 1: [64x256] @ [256x128] ----
    f32x4 acc[8] = {};
    for (int kk = 0; kk < 4; ++kk) {
        const int k0 = kk * 64;
        if (kk) __syncthreads();
#pragma unroll
        for (int p = 0; p < 2; ++p) {
            const int t = tid + p * 256;
            const int row = t >> 3, gs = ((t & 7) ^ (row & 7)) * 8;
            ld16(A + t * 8, Hin + (r0 + row) * 256 + k0 + gs);
        }
#pragma unroll
        for (int p = 0; p < 4; ++p) {
            const int t = tid + p * 256;
            const int row = t >> 3, gs = ((t & 7) ^ (row & 7)) * 8;
            ld16(Bb + t * 8, WT0 + row * 256 + k0 + gs);
        }
        __syncthreads();
#pragma unroll
        for (int ks = 0; ks < 2; ++ks) {
            const bf16x8 a = frag64(A, w * 16 + lr, ks * 4 + hi);
            bf16x8 b[8];
#pragma unroll
            for (int nb = 0; nb < 8; ++nb) b[nb] = frag64(Bb, nb * 16 + lr, ks * 4 + hi);
#pragma unroll
            for (int nb = 0; nb < 8; ++nb) acc[nb] = MFMA(a, b[nb], acc[nb]);
        }
    }
    // layer-1 epilogue -> H1 [64][128], chunk-swizzled like frag64 expects
#pragma unroll
    for (int nb = 0; nb < 8; ++nb) {
        const int col = nb * 16 + lr;
        const float bb = b0[col];
#pragma unroll
        for (int r = 0; r < 4; ++r) {
            const int rl = w * 16 + hi * 4 + r;
            float v = acc[nb][r] + bb;
            v = v > 0.0f ? v : 0.3f * v;
            H1[rl * 128 + (((col >> 3) ^ (rl & 7)) * 8) + (col & 7)] = (bf16)v;
        }
    }
    __syncthreads();
    // ---- layer 2: [64x128] @ [128x64] ----
    f32x4 acc2[4] = {};
    for (int kk = 0; kk < 2; ++kk) {
#pragma unroll
        for (int p = 0; p < 2; ++p) {
            const int t = tid + p * 256;
            const int row = t >> 3, gs = ((t & 7) ^ (row & 7)) * 8;
            ld16(Bb + t * 8, WT1 + row * 128 + kk * 64 + gs);
        }
        __syncthreads();
#pragma unroll
        for (int ks = 0; ks < 2; ++ks) {
            const int rl = w * 16 + lr;
            const int c = kk * 8 + ks * 4 + hi;           // global 16B chunk of K=128
            const bf16x8 a = *reinterpret_cast<const bf16x8*>(
                H1 + rl * 128 + ((c ^ (rl & 7)) * 8));
            bf16x8 b[4];
#pragma unroll
            for (int jj = 0; jj < 4; ++jj) b[jj] = frag64(Bb, jj * 16 + lr, ks * 4 + hi);
#pragma unroll
            for (int jj = 0; jj < 4; ++jj) acc2[jj] = MFMA(a, b[jj], acc2[jj]);
        }
        __syncthreads();
    }
    // ---- layer 3: per-row dot(64) + sigmoid (+scale), shfl reduce over lr ----
    float b1v[4], wfv[4];
#pragma unroll
    for (int jj = 0; jj < 4; ++jj) {
        b1v[jj] = b1[jj * 16 + lr];
        wfv[jj] = wf[jj * 16 + lr];
    }
    const float bfv = bf_[0];
#pragma unroll
    for (int r = 0; r < 4; ++r) {
        float p = 0.0f;
#pragma unroll
        for (int jj = 0; jj < 4; ++jj) {
            float v = acc2[jj][r] + b1v[jj];
            v = v > 0.0f ? v : 0.3f * v;
            p = fmaf(v, wfv[jj], p);
        }
        p += __shfl_xor(p, 1); p += __shfl_xor(p, 2);
        p += __shfl_xor(p, 4); p += __shfl_xor(p, 8);
        if (lr == 0) {
            const int row = r0 + w * 16 + hi * 4 + r;
            float res = sigf(p + bfv);
            if (scale) res *= scale[row];
            outp[row] = res;
        }
    }
}

// ---------------------------------------------------------------------------
extern "C" void kernel_launch(void* const* d_in, const int* in_sizes, int n_in,
                              void* d_out, int out_size, void* d_ws, size_t ws_size,
                              hipStream_t stream)
{
    const float* x         = (const float*)d_in[0];
    const float* click     = (const float*)d_in[1];
    const float* h_c       = (const float*)d_in[2];
    const float* h_v       = (const float*)d_in[3];
    const float* s_c       = (const float*)d_in[4];
    const float* s_v       = (const float*)d_in[5];
    const int*   g_prev    = (const int*)d_in[6];
    const float* Wx_c      = (const float*)d_in[7];
    const float* bx_c      = (const float*)d_in[8];
    const float* Wh_c      = (const float*)d_in[9];
    const float* Wx_v      = (const float*)d_in[10];
    const float* bx_v      = (const float*)d_in[11];
    const float* Wh_v      = (const float*)d_in[12];
    const float* W_schat_c = (const float*)d_in[13];
    const float* W_schat_v = (const float*)d_in[14];
    const float* W_svhat_v = (const float*)d_in[15];
    const float* W_svhat_c = (const float*)d_in[16];
    const float* Wpc0 = (const float*)d_in[17];
    const float* bpc0 = (const float*)d_in[18];
    const float* Wpc1 = (const float*)d_in[19];
    const float* bpc1 = (const float*)d_in[20];
    const float* Wfcc = (const float*)d_in[21];
    const float* bfcc = (const float*)d_in[22];
    const float* Wpv0 = (const float*)d_in[23];
    const float* bpv0 = (const float*)d_in[24];
    const float* Wpv1 = (const float*)d_in[25];
    const float* bpv1 = (const float*)d_in[26];
    const float* Wfcv = (const float*)d_in[27];
    const float* bfcv = (const float*)d_in[28];

    // output layout (fp32, concatenated in return order)
    float* out     = (float*)d_out;
    float* out_hcp = out;
    float* out_hvp = out + NB;
    float* out_hcn = out + 2 * NB;
    float* out_hvn = out_hcn + NB * NU;
    float* out_scn = out_hvn + NB * NU;
    float* out_svn = out_scn + NB * NU;
    float* out_gnw = out_svn + NB * NU;

    // workspace carve: gmask first (8B aligned), then bf16 buffers
    unsigned long long* gmask64 = (unsigned long long*)d_ws;   // 131072 u64 = 1 MB
    const unsigned* gmask32 = (const unsigned*)d_ws;
    bf16* w = (bf16*)d_ws + 524288;                            // skip 1 MB
    bf16* WTc    = w; w += 256 * 256;        // W_schat_c^T
    bf16* WTv    = w; w += 256 * 256;        // W_schat_v^T
    bf16* Wsv    = w; w += 256 * 512;        // [W_svhat_v ; W_svhat_c]^T concat-K
    bf16* WT_pc0 = w; w += 128 * 256;
    bf16* WT_pv0 = w; w += 128 * 256;
    bf16* WT_pc1 = w; w += 64 * 128;
    bf16* WT_pv1 = w; w += 64 * 128;
    bf16* WgT_c  = w; w += 4 * 256 * 512;
    bf16* WgT_v  = w; w += 4 * 256 * 512;
    bf16* xs     = w; w += NB * 512;         // [x_bf | s_hat] (both branches)
    bf16* hv_cat = w; w += NB * 512;         // [h_v_bf | click-masked h_c_n]
    bf16* buf256 = w; w += NB * 256;         // h_c_bf -> hcnb -> hvnb (aliased)

    // --- weight prep jobs ---
    TrJobs J;
    int j = 0;
    J.src[j] = W_schat_c; J.dst[j] = WTc; J.R[j] = 256; J.C[j] = 256; J.dstr[j] = 256; ++j;
    J.src[j] = W_schat_v; J.dst[j] = WTv; J.R[j] = 256; J.C[j] = 256; J.dstr[j] = 256; ++j;
    J.src[j] = W_svhat_v; J.dst[j] = Wsv;       J.R[j] = 256; J.C[j] = 256; J.dstr[j] = 512; ++j;
    J.src[j] = W_svhat_c; J.dst[j] = Wsv + 256; J.R[j] = 256; J.C[j] = 256; J.dstr[j] = 512; ++j;
    J.src[j] = Wpc0; J.dst[j] = WT_pc0; J.R[j] = 256; J.C[j] = 128; J.dstr[j] = 256; ++j;
    J.src[j] = Wpv0; J.dst[j] = WT_pv0; J.R[j] = 256; J.C[j] = 128; J.dstr[j] = 256; ++j;
    J.src[j] = Wpc1; J.dst[j] = WT_pc1; J.R[j] = 128; J.C[j] = 64;  J.dstr[j] = 128; ++j;
    J.src[j] = Wpv1; J.dst[j] = WT_pv1; J.R[j] = 128; J.C[j] = 64;  J.dstr[j] = 128; ++j;
    for (int g = 0; g < 4; ++g) {
        J.src[j] = Wx_c + g * 65536; J.dst[j] = WgT_c + g * 131072;       J.R[j] = 256; J.C[j] = 256; J.dstr[j] = 512; ++j;
        J.src[j] = Wh_c + g * 65536; J.dst[j] = WgT_c + g * 131072 + 256; J.R[j] = 256; J.C[j] = 256; J.dstr[j] = 512; ++j;
    }
    for (int g = 0; g < 4; ++g) {
        J.src[j] = Wx_v + g * 65536; J.dst[j] = WgT_v + g * 131072;       J.R[j] = 256; J.C[j] = 256; J.dstr[j] = 512; ++j;
        J.src[j] = Wh_v + g * 65536; J.dst[j] = WgT_v + g * 131072 + 256; J.R[j] = 256; J.C[j] = 256; J.dstr[j] = 512; ++j;
    }

    // fused prologue: cvt (y=0..2) + tr (y=3) + pack (y=4), one launch
    k_pre<<<dim3(4096, 5), 256, 0, stream>>>(x, h_v, h_c, xs, hv_cat, buf256,
                                             g_prev, gmask64, J);

    // click branch
    k_schat_t<<<dim3(512, 4), 256, 0, stream>>>(buf256, hv_cat, WTc, WTv, gmask32, xs);
    k_gates_t<<<dim3(512, 8), 256, 0, stream>>>(xs, WgT_c, bx_c, click, gmask32, s_c,
                                                nullptr, out_scn, out_hcn, nullptr,
                                                buf256, hv_cat, 0);
    k_mlp_f<<<512, 256, 0, stream>>>(buf256, WT_pc0, bpc0, WT_pc1, bpc1,
                                     Wfcc, bfcc, nullptr, out_hcp);

    // conversion branch
    k_svhat_t<<<dim3(512, 2), 256, 0, stream>>>(hv_cat, Wsv, xs);
    k_gates_t<<<dim3(512, 8), 256, 0, stream>>>(xs, WgT_v, bx_v, click, gmask32, s_v,
                                                h_v, out_svn, out_hvn, out_gnw,
                                                buf256, nullptr, 1);
    k_mlp_f<<<512, 256, 0, stream>>>(buf256, WT_pv0, bpv0, WT_pv1, bpv1,
                                     Wfcv, bfcv, out_hcp, out_hvp);
}

// Round 14
// 572.776 us; speedup vs baseline: 1.0838x; 1.0158x over previous
//
#include <hip/hip_runtime.h>
#include <hip/hip_bf16.h>
#include <math.h>

typedef __bf16 bf16;
typedef __bf16 bf16x8 __attribute__((ext_vector_type(8)));
typedef float  f32x4  __attribute__((ext_vector_type(4)));

#define NB 32768   // batch
#define NU 256     // units (= D)

#define MFMA(a,b,c) __builtin_amdgcn_mfma_f32_16x16x32_bf16((a),(b),(c),0,0,0)

// fast activations: v_rcp + v_exp based (absmax headroom is ~2^-5, these are ~1ulp)
static __device__ __forceinline__ float sigf(float x) {
    return __builtin_amdgcn_rcpf(1.0f + __expf(-x));
}
static __device__ __forceinline__ float tanh_(float x) {
    return fmaf(2.0f, sigf(2.0f * x), -1.0f);   // tanh = 2*sigmoid(2x) - 1
}

// async global->LDS, 16 B per lane. LDS dest must be thread-contiguous
// (base + tid*16); global src is per-lane arbitrary (16B-aligned).
static __device__ __forceinline__ void ld16(bf16* l, const bf16* g) {
    __builtin_amdgcn_global_load_lds(
        (const __attribute__((address_space(1))) void*)g,
        (__attribute__((address_space(3))) void*)l, 16, 0, 0);
}

// Swizzled LDS tile [rows][64] bf16 (128 B/row, 8x 16B chunks).
// Global chunk kc is stored at LDS slot kc^(row&7) (staged via pre-swizzled
// global source address; LDS dest stays linear). 16 lanes reading the same kc
// across consecutive rows then hit 8 distinct 4-bank columns -> conflict-free.
static __device__ __forceinline__ bf16x8 frag64(const bf16* buf, int row, int kc) {
    return *reinterpret_cast<const bf16x8*>(buf + row * 64 + ((kc ^ (row & 7)) * 8));
}

// ---------------------------------------------------------------------------
// Fused prologue: all independent prep work in ONE launch.
//  y=0: x    -> xs[:,0:256]      (bf16, stride 512)
//  y=1: h_v  -> hv_cat[:,0:256]  (bf16, stride 512)
//  y=2: h_c  -> buf256           (bf16, stride 256)
//  y=3: 24 transpose jobs (x = job*64 + tile), 32x32 tiles, fp32 -> bf16^T
//  y=4: pack g_prev>0 bitmask (x < 1024)
// ---------------------------------------------------------------------------
struct TrJobs {
    const float* src[24];
    bf16*        dst[24];
    int R[24], C[24], dstr[24];
};

__global__ void k_pre(const float* __restrict__ x, const float* __restrict__ h_v,
                      const float* __restrict__ h_c,
                      bf16* __restrict__ xs, bf16* __restrict__ hv_cat,
                      bf16* __restrict__ hcb,
                      const int* __restrict__ g, unsigned long long* __restrict__ m,
                      TrJobs J)
{
    __shared__ float tile[32][33];
    const int yy = blockIdx.y;
    if (yy < 3) {
        // fp32 -> bf16 conversion jobs
        const int gid = blockIdx.x * 256 + threadIdx.x;   // 8-element index
        const int row = gid >> 5, col = (gid & 31) * 8;
        const float* src = (yy == 0) ? x : (yy == 1) ? h_v : h_c;
        bf16* dst; int stride;
        if (yy == 0)      { dst = xs;     stride = 512; }
        else if (yy == 1) { dst = hv_cat; stride = 512; }
        else              { dst = hcb;    stride = 256; }
        const f32x4* s4 = reinterpret_cast<const f32x4*>(src + row * 256 + col);
        const f32x4 a = s4[0], b = s4[1];
        bf16x8 o;
        o[0] = (bf16)a[0]; o[1] = (bf16)a[1]; o[2] = (bf16)a[2]; o[3] = (bf16)a[3];
        o[4] = (bf16)b[0]; o[5] = (bf16)b[1]; o[6] = (bf16)b[2]; o[7] = (bf16)b[3];
        *reinterpret_cast<bf16x8*>(dst + row * stride + col) = o;
    } else if (yy == 3) {
        // tiled transpose jobs
        const int bx = blockIdx.x;
        if (bx >= 24 * 64) return;
        const int j = bx >> 6, tl = bx & 63;
        const int R = J.R[j], C = J.C[j], dstr = J.dstr[j];
        const int tilesC = C >> 5;
        const int tr = tl / tilesC, tc = tl % tilesC;
        if (tr >= (R >> 5)) return;
        const int r0 = tr * 32, c0 = tc * 32;
        const int tx = threadIdx.x & 31, ty = threadIdx.x >> 5;   // (32,8)
        const float* src = J.src[j];
        bf16* dst = J.dst[j];
#pragma unroll
        for (int i = 0; i < 4; ++i)
            tile[ty + 8 * i][tx] = src[(r0 + ty + 8 * i) * C + c0 + tx];
        __syncthreads();
#pragma unroll
        for (int i = 0; i < 4; ++i)
            dst[(c0 + ty + 8 * i) * dstr + r0 + tx] = (bf16)tile[tx][ty + 8 * i];
    } else if (yy == 4) {
        // bitmask pack: 33.5 MB int32 -> 1 MB
        if (blockIdx.x >= 1024) return;
        const int tid0 = blockIdx.x * 256 + threadIdx.x;
#pragma unroll
        for (int it = 0; it < 32; ++it) {
            const int i = tid0 + it * (1024 * 256);
            const unsigned long long b = __ballot(g[i] > 0);
            if ((threadIdx.x & 63) == 0) m[i >> 6] = b;
        }
    }
}

// ---------------------------------------------------------------------------
// s_c_hat = where(g_prev>0, h_v@Wv, h_c@Wc) -> xs[:,256:512] (bf16)
// dual GEMM, register-diet tile: block 64 rows x 64 cols, 4 waves each 16x64.
// 1D grid 2048 + XCD-chunked swizzle: the 4 c0-blocks sharing one A-panel are
// swz-consecutive AND same bid%8 -> same XCD -> panel L2-resident, fetched 1x.
// ---------------------------------------------------------------------------
__global__ __launch_bounds__(256) void k_schat_t(
    const bf16* __restrict__ hc, const bf16* __restrict__ hvcat,
    const bf16* __restrict__ WTc, const bf16* __restrict__ WTv,
    const unsigned* __restrict__ gmask, bf16* __restrict__ xs)
{
    __shared__ bf16 A1[64 * 64], A2[64 * 64], B1[64 * 64], B2[64 * 64];  // 32 KB
    const int tid = threadIdx.x, lane = tid & 63, w = tid >> 6;
    const int lr = lane & 15, hi = lane >> 4;
    const int bid = blockIdx.x;                       // 2048 blocks
    const int swz = (bid & 7) * 256 + (bid >> 3);     // XCD-chunked bijection
    const int r0 = (swz >> 2) * 64, c0 = (swz & 3) * 64;
    f32x4 acc1[4] = {}, acc2[4] = {};
    for (int kk = 0; kk < 4; ++kk) {
        const int k0 = kk * 64;
        if (kk) __syncthreads();
#pragma unroll
        for (int p = 0; p < 2; ++p) {
            const int t = tid + p * 256;
            const int row = t >> 3, gs = ((t & 7) ^ (row & 7)) * 8;
            ld16(A1 + t * 8, hc    + (r0 + row) * 256 + k0 + gs);
            ld16(A2 + t * 8, hvcat + (r0 + row) * 512 + k0 + gs);
            ld16(B1 + t * 8, WTc   + (c0 + row) * 256 + k0 + gs);
            ld16(B2 + t * 8, WTv   + (c0 + row) * 256 + k0 + gs);
        }
        __syncthreads();
#pragma unroll
        for (int ks = 0; ks < 2; ++ks) {
            const bf16x8 a1 = frag64(A1, w * 16 + lr, ks * 4 + hi);
            const bf16x8 a2 = frag64(A2, w * 16 + lr, ks * 4 + hi);
            bf16x8 b1[4], b2[4];
#pragma unroll
            for (int jj = 0; jj < 4; ++jj) {
                b1[jj] = frag64(B1, jj * 16 + lr, ks * 4 + hi);
                b2[jj] = frag64(B2, jj * 16 + lr, ks * 4 + hi);
            }
#pragma unroll
            for (int jj = 0; jj < 4; ++jj) {
                acc1[jj] = MFMA(a1, b1[jj], acc1[jj]);
                acc2[jj] = MFMA(a2, b2[jj], acc2[jj]);
            }
        }
    }
#pragma unroll
    for (int jj = 0; jj < 4; ++jj)
#pragma unroll
        for (int r = 0; r < 4; ++r) {
            const int row = r0 + w * 16 + hi * 4 + r;
            const int col = c0 + jj * 16 + lr;
            const bool gp = (gmask[row * 8 + (col >> 5)] >> (col & 31)) & 1;
            xs[row * 512 + 256 + col] = (bf16)(gp ? acc2[jj][r] : acc1[jj][r]);
        }
}

// ---------------------------------------------------------------------------
// s_v_hat = hv_cat @ Wsv -> xs[:,256:512]; K=512, register-diet tile
// 64 rows x 128 cols; 1D grid 1024 + XCD-chunked swizzle (2 c0 share A-panel).
// ---------------------------------------------------------------------------
__global__ __launch_bounds__(256) void k_svhat_t(
    const bf16* __restrict__ hvcat, const bf16* __restrict__ Wsv,
    bf16* __restrict__ xs)
{
    __shared__ bf16 A[64 * 64], B[128 * 64];       // 8 KB + 16 KB
    const int tid = threadIdx.x, lane = tid & 63, w = tid >> 6;
    const int lr = lane & 15, hi = lane >> 4;
    const int bid = blockIdx.x;                       // 1024 blocks
    const int swz = (bid & 7) * 128 + (bid >> 3);     // XCD-chunked bijection
    const int r0 = (swz >> 1) * 64, c0 = (swz & 1) * 128;
    f32x4 acc[8] = {};
    for (int kk = 0; kk < 8; ++kk) {
        const int k0 = kk * 64;
        if (kk) __syncthreads();
#pragma unroll
        for (int p = 0; p < 2; ++p) {
            const int t = tid + p * 256;
            const int row = t >> 3, gs = ((t & 7) ^ (row & 7)) * 8;
            ld16(A + t * 8, hvcat + (r0 + row) * 512 + k0 + gs);
        }
#pragma unroll
        for (int p = 0; p < 4; ++p) {
            const int t = tid + p * 256;
            const int row = t >> 3, gs = ((t & 7) ^ (row & 7)) * 8;
            ld16(B + t * 8, Wsv + (c0 + row) * 512 + k0 + gs);
        }
        __syncthreads();
#pragma unroll
        for (int ks = 0; ks < 2; ++ks) {
            const bf16x8 a = frag64(A, w * 16 + lr, ks * 4 + hi);
            bf16x8 b[8];
#pragma unroll
            for (int jj = 0; jj < 8; ++jj) b[jj] = frag64(B, jj * 16 + lr, ks * 4 + hi);
#pragma unroll
            for (int jj = 0; jj < 8; ++jj) acc[jj] = MFMA(a, b[jj], acc[jj]);
        }
    }
#pragma unroll
    for (int jj = 0; jj < 8; ++jj)
#pragma unroll
        for (int r = 0; r < 4; ++r) {
            const int row = r0 + w * 16 + hi * 4 + r;
            const int col = c0 + jj * 16 + lr;
            xs[row * 512 + 256 + col] = (bf16)acc[jj][r];
        }
}

// ---------------------------------------------------------------------------
// Gates GEMM + cell update. A = xs (K=512, BK=64); B tile = 4 gates x 32 u.
// Register-diet tile 64 rows x 128 cols (r9: VGPR 52, occ 38%, 105 us).
// 1D grid 4096 + XCD-chunked swizzle: the 8 u0-blocks sharing one 64-row
// xs panel (64 KB) are swz-consecutive and same bid%8 -> same XCD ->
// panel fetched once into that XCD's L2 (each chunk = 64 panels = 4 MB = L2).
// mode 0 = click branch, mode 1 = conversion branch.
// ---------------------------------------------------------------------------
__global__ __launch_bounds__(256) void k_gates_t(
    const bf16* __restrict__ xs, const bf16* __restrict__ WgT,
    const float* __restrict__ bx, const float* __restrict__ click,
    const unsigned* __restrict__ gmask, const float* __restrict__ s_prev,
    const float* __restrict__ h_prev,
    float* __restrict__ out_s, float* __restrict__ out_h,
    float* __restrict__ out_g, bf16* __restrict__ hnb,
    bf16* __restrict__ hmask_dst, int mode)
{
    __shared__ bf16 A[64 * 64], B[128 * 64];       // 8 KB + 16 KB
    const int tid = threadIdx.x, lane = tid & 63, w = tid >> 6;
    const int lr = lane & 15, hi = lane >> 4;
    const int bid = blockIdx.x;                       // 4096 blocks
    const int swz = (bid & 7) * 512 + (bid >> 3);     // XCD-chunked bijection
    const int r0 = (swz >> 3) * 64, u0 = (swz & 7) * 32;
    f32x4 acc[8] = {};
    for (int kk = 0; kk < 8; ++kk) {
        const int k0 = kk * 64;
        if (kk) __syncthreads();
#pragma unroll
        for (int p = 0; p < 2; ++p) {
            const int t = tid + p * 256;
            const int row = t >> 3, gs = ((t & 7) ^ (row & 7)) * 8;
            ld16(A + t * 8, xs + (r0 + row) * 512 + k0 + gs);
        }
#pragma unroll
        for (int p = 0; p < 4; ++p) {
            const int t = tid + p * 256;
            const int row = t >> 3, gs = ((t & 7) ^ (row & 7)) * 8;
            const int g = row >> 5, ul = row & 31;
            ld16(B + t * 8, WgT + (g * 256 + u0 + ul) * 512 + k0 + gs);
        }
        __syncthreads();
#pragma unroll
        for (int ks = 0; ks < 2; ++ks) {
            const bf16x8 a = frag64(A, w * 16 + lr, ks * 4 + hi);
            bf16x8 b[8];
#pragma unroll
            for (int nb = 0; nb < 8; ++nb) b[nb] = frag64(B, nb * 16 + lr, ks * 4 + hi);
#pragma unroll
            for (int nb = 0; nb < 8; ++nb) acc[nb] = MFMA(a, b[nb], acc[nb]);
        }
    }
    // epilogue: gate gg lives in acc[gg*2 + uh]
    const int u0b = u0 >> 5;
    float bfv[2], biv[2], bov[2], bgv[2];
#pragma unroll
    for (int uh = 0; uh < 2; ++uh) {
        const int u = u0 + uh * 16 + lr;
        bfv[uh] = bx[u];       biv[uh] = bx[256 + u];
        bov[uh] = bx[512 + u]; bgv[uh] = bx[768 + u];
    }
#pragma unroll
    for (int r = 0; r < 4; ++r) {
        const int row = r0 + w * 16 + hi * 4 + r;
        const float ck = click[row];
        const unsigned mw = (mode == 0) ? gmask[row * 8 + u0b] : 0u;
#pragma unroll
        for (int uh = 0; uh < 2; ++uh) {
            const int u = u0 + uh * 16 + lr;
            const int o = row * 256 + u;
            const float f  = sigf(acc[0 + uh][r] + bfv[uh]);
            const float ii = sigf(acc[2 + uh][r] + biv[uh]);
            const float oo = sigf(acc[4 + uh][r] + bov[uh]);
            const float gg = tanh_(acc[6 + uh][r] + bgv[uh]);
            if (mode == 0) {
                const bool gp = (mw >> (u & 31)) & 1;
                const float sn = ii * gg + (gp ? 0.0f : f * s_prev[o]);
                const float hn = oo * tanh_(sn);
                out_s[o] = sn;
                out_h[o] = hn;
                hnb[o]   = (bf16)hn;
                hmask_dst[row * 512 + 256 + u] =
                    (ck >= 0.5f) ? (bf16)hn : (bf16)0.0f;
            } else {
                const bool m = ck >= 0.5f;
                const float sv = s_prev[o];
                const float sn = m ? (f * sv + ii * gg) : sv;
                const float hn = m ? (oo * tanh_(sn)) : h_prev[o];
                out_s[o] = sn;
                out_h[o] = hn;
                out_g[o] = m ? 1.0f : 0.0f;
                hnb[o]   = (bf16)hn;
            }
        }
    }
}

// ---------------------------------------------------------------------------
// Fused MLP: leaky(H@W0+b0) -> leaky(@W1+b1) -> sigmoid(dot(wf)+bf) [*scale]
// One block = 64 rows; 4 waves x 16 rows; layer-1 output kept in LDS (swizzled)
// ---------------------------------------------------------------------------
__global__ __launch_bounds__(256) void k_mlp_f(
    const bf16* __restrict__ Hin,          // [NB][256]
    const bf16* __restrict__ WT0,          // [128][256]
    const float* __restrict__ b0,          // [128]
    const bf16* __restrict__ WT1,          // [64][128]
    const float* __restrict__ b1,          // [64]
    const float* __restrict__ wf,          // [64]
    const float* __restrict__ bf_,         // [1]
    const float* __restrict__ scale,       // null or [NB]
    float* __restrict__ outp)              // [NB]
{
    __shared__ bf16 A[64 * 64], Bb[128 * 64], H1[64 * 128];
    const int tid = threadIdx.x, lane = tid & 63, w = tid >> 6;
    const int lr = lane & 15, hi = lane >> 4;
    const int r0 = blockIdx.x * 64;
    // ---- layer 1: [64x256] @ [256x128] ----
    f32x4 acc[8] = {};
    for (int kk = 0; kk < 4; ++kk) {
        const int k0 = kk * 64;
        if (kk) __syncthreads();
#pragma unroll
        for (int p = 0; p < 2; ++p) {
            const int t = tid + p * 256;
            const int row = t >> 3, gs = ((t & 7) ^ (row & 7)) * 8;
            ld16(A + t * 8, Hin + (r0 + row) * 256 + k0 + gs);
        }
#pragma unroll
        for (int p = 0; p < 4; ++p) {
            const int t = tid + p * 256;
            const int row = t >> 3, gs = ((t & 7) ^ (row & 7)) * 8;
            ld16(Bb + t * 8, WT0 + row * 256 + k0 + gs);
        }
        __syncthreads();
#pragma unroll
        for (int ks = 0; ks < 2; ++ks) {
            const bf16x8 a = frag64(A, w * 16 + lr, ks * 4 + hi);
            bf16x8 b[8];
#pragma unroll
            for (int nb = 0; nb < 8; ++nb) b[nb] = frag64(Bb, nb * 16 + lr, ks * 4 + hi);
#pragma unroll
            for (int nb = 0; nb < 8; ++nb) acc[nb] = MFMA(a, b[nb], acc[nb]);
        }
    }
    // layer-1 epilogue -> H1 [64][128], chunk-swizzled like frag64 expects
#pragma unroll
    for (int nb = 0; nb < 8; ++nb) {
        const int col = nb * 16 + lr;
        const float bb = b0[col];
#pragma unroll
        for (int r = 0; r < 4; ++r) {
            const int rl = w * 16 + hi * 4 + r;
            float v = acc[nb][r] + bb;
            v = v > 0.0f ? v : 0.3f * v;
            H1[rl * 128 + (((col >> 3) ^ (rl & 7)) * 8) + (col & 7)] = (bf16)v;
        }
    }
    __syncthreads();
    // ---- layer 2: [64x128] @ [128x64] ----
    f32x4 acc2[4] = {};
    for (int kk = 0; kk < 2; ++kk) {
#pragma unroll
        for (int p = 0; p < 2; ++p) {
            const int t = tid + p * 256;
            const int row = t >> 3, gs = ((t & 7) ^ (row & 7)) * 8;
            ld16(Bb + t * 8, WT1 + row * 128 + kk * 64 + gs);
        }
        __syncthreads();
#pragma unroll
        for (int ks = 0; ks < 2; ++ks) {
            const int rl = w * 16 + lr;
            const int c = kk * 8 + ks * 4 + hi;           // global 16B chunk of K=128
            const bf16x8 a = *reinterpret_cast<const bf16x8*>(
                H1 + rl * 128 + ((c ^ (rl & 7)) * 8));
            bf16x8 b[4];
#pragma unroll
            for (int jj = 0; jj < 4; ++jj) b[jj] = frag64(Bb, jj * 16 + lr, ks * 4 + hi);
#pragma unroll
            for (int jj = 0; jj < 4; ++jj) acc2[jj] = MFMA(a, b[jj], acc2[jj]);
        }
        __syncthreads();
    }
    // ---- layer 3: per-row dot(64) + sigmoid (+scale), shfl reduce over lr ----
    float b1v[4], wfv[4];
#pragma unroll
    for (int jj = 0; jj < 4; ++jj) {
        b1v[jj] = b1[jj * 16 + lr];
        wfv[jj] = wf[jj * 16 + lr];
    }
    const float bfv = bf_[0];
#pragma unroll
    for (int r = 0; r < 4; ++r) {
        float p = 0.0f;
#pragma unroll
        for (int jj = 0; jj < 4; ++jj) {
            float v = acc2[jj][r] + b1v[jj];
            v = v > 0.0f ? v : 0.3f * v;
            p = fmaf(v, wfv[jj], p);
        }
        p += __shfl_xor(p, 1); p += __shfl_xor(p, 2);
        p += __shfl_xor(p, 4); p += __shfl_xor(p, 8);
        if (lr == 0) {
            const int row = r0 + w * 16 + hi * 4 + r;
            float res = sigf(p + bfv);
            if (scale) res *= scale[row];
            outp[row] = res;
        }
    }
}

// ---------------------------------------------------------------------------
extern "C" void kernel_launch(void* const* d_in, const int* in_sizes, int n_in,
                              void* d_out, int out_size, void* d_ws, size_t ws_size,
                              hipStream_t stream)
{
    const float* x         = (const float*)d_in[0];
    const float* click     = (const float*)d_in[1];
    const float* h_c       = (const float*)d_in[2];
    const float* h_v       = (const float*)d_in[3];
    const float* s_c       = (const float*)d_in[4];
    const float* s_v       = (const float*)d_in[5];
    const int*   g_prev    = (const int*)d_in[6];
    const float* Wx_c      = (const float*)d_in[7];
    const float* bx_c      = (const float*)d_in[8];
    const float* Wh_c      = (const float*)d_in[9];
    const float* Wx_v      = (const float*)d_in[10];
    const float* bx_v      = (const float*)d_in[11];
    const float* Wh_v      = (const float*)d_in[12];
    const float* W_schat_c = (const float*)d_in[13];
    const float* W_schat_v = (const float*)d_in[14];
    const float* W_svhat_v = (const float*)d_in[15];
    const float* W_svhat_c = (const float*)d_in[16];
    const float* Wpc0 = (const float*)d_in[17];
    const float* bpc0 = (const float*)d_in[18];
    const float* Wpc1 = (const float*)d_in[19];
    const float* bpc1 = (const float*)d_in[20];
    const float* Wfcc = (const float*)d_in[21];
    const float* bfcc = (const float*)d_in[22];
    const float* Wpv0 = (const float*)d_in[23];
    const float* bpv0 = (const float*)d_in[24];
    const float* Wpv1 = (const float*)d_in[25];
    const float* bpv1 = (const float*)d_in[26];
    const float* Wfcv = (const float*)d_in[27];
    const float* bfcv = (const float*)d_in[28];

    // output layout (fp32, concatenated in return order)
    float* out     = (float*)d_out;
    float* out_hcp = out;
    float* out_hvp = out + NB;
    float* out_hcn = out + 2 * NB;
    float* out_hvn = out_hcn + NB * NU;
    float* out_scn = out_hvn + NB * NU;
    float* out_svn = out_scn + NB * NU;
    float* out_gnw = out_svn + NB * NU;

    // workspace carve: gmask first (8B aligned), then bf16 buffers
    unsigned long long* gmask64 = (unsigned long long*)d_ws;   // 131072 u64 = 1 MB
    const unsigned* gmask32 = (const unsigned*)d_ws;
    bf16* w = (bf16*)d_ws + 524288;                            // skip 1 MB
    bf16* WTc    = w; w += 256 * 256;        // W_schat_c^T
    bf16* WTv    = w; w += 256 * 256;        // W_schat_v^T
    bf16* Wsv    = w; w += 256 * 512;        // [W_svhat_v ; W_svhat_c]^T concat-K
    bf16* WT_pc0 = w; w += 128 * 256;
    bf16* WT_pv0 = w; w += 128 * 256;
    bf16* WT_pc1 = w; w += 64 * 128;
    bf16* WT_pv1 = w; w += 64 * 128;
    bf16* WgT_c  = w; w += 4 * 256 * 512;
    bf16* WgT_v  = w; w += 4 * 256 * 512;
    bf16* xs     = w; w += NB * 512;         // [x_bf | s_hat] (both branches)
    bf16* hv_cat = w; w += NB * 512;         // [h_v_bf | click-masked h_c_n]
    bf16* buf256 = w; w += NB * 256;         // h_c_bf -> hcnb -> hvnb (aliased)

    // --- weight prep jobs ---
    TrJobs J;
    int j = 0;
    J.src[j] = W_schat_c; J.dst[j] = WTc; J.R[j] = 256; J.C[j] = 256; J.dstr[j] = 256; ++j;
    J.src[j] = W_schat_v; J.dst[j] = WTv; J.R[j] = 256; J.C[j] = 256; J.dstr[j] = 256; ++j;
    J.src[j] = W_svhat_v; J.dst[j] = Wsv;       J.R[j] = 256; J.C[j] = 256; J.dstr[j] = 512; ++j;
    J.src[j] = W_svhat_c; J.dst[j] = Wsv + 256; J.R[j] = 256; J.C[j] = 256; J.dstr[j] = 512; ++j;
    J.src[j] = Wpc0; J.dst[j] = WT_pc0; J.R[j] = 256; J.C[j] = 128; J.dstr[j] = 256; ++j;
    J.src[j] = Wpv0; J.dst[j] = WT_pv0; J.R[j] = 256; J.C[j] = 128; J.dstr[j] = 256; ++j;
    J.src[j] = Wpc1; J.dst[j] = WT_pc1; J.R[j] = 128; J.C[j] = 64;  J.dstr[j] = 128; ++j;
    J.src[j] = Wpv1; J.dst[j] = WT_pv1; J.R[j] = 128; J.C[j] = 64;  J.dstr[j] = 128; ++j;
    for (int g = 0; g < 4; ++g) {
        J.src[j] = Wx_c + g * 65536; J.dst[j] = WgT_c + g * 131072;       J.R[j] = 256; J.C[j] = 256; J.dstr[j] = 512; ++j;
        J.src[j] = Wh_c + g * 65536; J.dst[j] = WgT_c + g * 131072 + 256; J.R[j] = 256; J.C[j] = 256; J.dstr[j] = 512; ++j;
    }
    for (int g = 0; g < 4; ++g) {
        J.src[j] = Wx_v + g * 65536; J.dst[j] = WgT_v + g * 131072;       J.R[j] = 256; J.C[j] = 256; J.dstr[j] = 512; ++j;
        J.src[j] = Wh_v + g * 65536; J.dst[j] = WgT_v + g * 131072 + 256; J.R[j] = 256; J.C[j] = 256; J.dstr[j] = 512; ++j;
    }

    // fused prologue: cvt (y=0..2) + tr (y=3) + pack (y=4), one launch
    k_pre<<<dim3(4096, 5), 256, 0, stream>>>(x, h_v, h_c, xs, hv_cat, buf256,
                                             g_prev, gmask64, J);

    // click branch
    k_schat_t<<<2048, 256, 0, stream>>>(buf256, hv_cat, WTc, WTv, gmask32, xs);
    k_gates_t<<<4096, 256, 0, stream>>>(xs, WgT_c, bx_c, click, gmask32, s_c,
                                        nullptr, out_scn, out_hcn, nullptr,
                                        buf256, hv_cat, 0);
    k_mlp_f<<<512, 256, 0, stream>>>(buf256, WT_pc0, bpc0, WT_pc1, bpc1,
                                     Wfcc, bfcc, nullptr, out_hcp);

    // conversion branch
    k_svhat_t<<<1024, 256, 0, stream>>>(hv_cat, Wsv, xs);
    k_gates_t<<<4096, 256, 0, stream>>>(xs, WgT_v, bx_v, click, gmask32, s_v,
                                        h_v, out_svn, out_hvn, out_gnw,
                                        buf256, nullptr, 1);
    k_mlp_f<<<512, 256, 0, stream>>>(buf256, WT_pv0, bpv0, WT_pv1, bpv1,
                                     Wfcv, bfcv, out_hcp, out_hvp);
}